// Round 4
// baseline (248.860 us; speedup 1.0000x reference)
//
#include <hip/hip_runtime.h>
#include <math.h>

// Problem constants
#define BB 32
#define CC 122
#define TT 500
#define SS 13
#define WID 80
#define EMB 8
#define PROJ 1024
#define HID 768
#define TP 96          // pooled time length
#define EPSF 1e-5f
#define KP 9760        // conv2 flat K' = 122*80
#define KSPLIT 16      // 16 chunks x 4 c-pairs (c-pairs 61..63 are zero/skip)

typedef float f32x4 __attribute__((ext_vector_type(4)));
typedef __bf16 bf16x8 __attribute__((ext_vector_type(8)));
typedef unsigned short u16x8 __attribute__((ext_vector_type(8)));
union BF8 { u16x8 u; bf16x8 b; };

// float -> bf16 bits, round-to-nearest-even
__device__ __forceinline__ unsigned short f2bf(float f) {
    union { float f; unsigned u; } v; v.f = f;
    unsigned r = v.u + 0x7FFFu + ((v.u >> 16) & 1u);
    return (unsigned short)(r >> 16);
}

// bf16 bits -> float (exact)
__device__ __forceinline__ float bf2f(unsigned short u) {
    union { unsigned u; float f; } v; v.u = (unsigned)u << 16;
    return v.f;
}

__device__ __forceinline__ float eluf(float x) {
    return x > 0.f ? x : __expf(x) - 1.f;
}

// ---------------- workspace layout (float offsets) ----------------
#define OFF_E    ((size_t)0)            // oute (B,C,T) f32        1,952,000
#define OFF_XB   ((size_t)1952000)      // x_bf (B,128,512) bf16
#define OFF_WB   ((size_t)3000576)      // W_bf (S,512,512) bf16
#define OFF_W2P  ((size_t)4704512)      // w2p (80,9760) bf16
#define OFF_PART ((size_t)20086272)     // (KSPLIT,B,WID,TP) f32
#define OFF_Z    ((size_t)24018432)     // z_bf (B,HID) bf16
#define OFF_Z1   ((size_t)24030720)     // z1 (B,PROJ) f32
#define OFF_G    ((size_t)24063488)     // g_bf (B,PROJ) bf16
#define OFF_Y    ((size_t)24079872)     // y (B,PROJ) f32 (unused as of r4)
#define OFF_W1B  ((size_t)24112640)     // w1b (PROJ,HID) bf16
#define OFF_W2B  ((size_t)24505856)     // w2b (PROJ,PROJ) bf16
#define OFF_WCB  ((size_t)25030144)     // wcb (80,32) bf16
#define OFF_B1F  ((size_t)25031424)     // (WID)
#define OFF_SC2  ((size_t)25031504)     // (WID)
#define OFF_SH2  ((size_t)25031584)     // (WID)

// pack region sizes (elements)
#define NPK_X  (2097152)   // 32*128*512
#define NPK_W  (3407872)   // 13*512*512
#define NPK_W2 (780800)    // 80*9760
#define NPK_M1 (786432)    // 1024*768
#define NPK_M2 (1048576)   // 1024*1024
#define NPK_TOT (NPK_X + NPK_W + NPK_W2 + NPK_M1 + NPK_M2)

// ---------------- pack (bf16 staging) + prep (block 0) ----------------
__global__ __launch_bounds__(256) void k_pack(const float* __restrict__ x,
                                              const float* __restrict__ W_sub,
                                              const float* __restrict__ conv2_w,
                                              const float* __restrict__ mlp1_w,
                                              const float* __restrict__ mlp2_w,
                                              const float* __restrict__ conv1_w, const float* __restrict__ conv1_b,
                                              const float* __restrict__ g1, const float* __restrict__ b1,
                                              const float* __restrict__ m1, const float* __restrict__ v1,
                                              const float* __restrict__ conv2_b, const float* __restrict__ g2,
                                              const float* __restrict__ b2, const float* __restrict__ m2,
                                              const float* __restrict__ v2,
                                              unsigned short* __restrict__ xb,
                                              unsigned short* __restrict__ wb,
                                              unsigned short* __restrict__ w2p,
                                              unsigned short* __restrict__ w1b,
                                              unsigned short* __restrict__ w2b,
                                              unsigned short* __restrict__ wcb, float* __restrict__ bias1f,
                                              float* __restrict__ scale2, float* __restrict__ shift2f) {
    if (blockIdx.x == 0) {
        int o = threadIdx.x;
        if (o < WID) {
            float s1 = g1[o] * rsqrtf(v1[o] + EPSF);
            float sh1 = b1[o] - m1[o] * s1;
            #pragma unroll
            for (int d = 0; d < 21; d++) {
                int klo = d - 16; if (klo < 0) klo = 0;
                int khi = d;      if (khi > 4) khi = 4;
                float acc = 0.f;
                for (int k = klo; k <= khi; k++) acc += conv1_w[o*5 + k];
                wcb[o*32 + d] = f2bf(acc * s1 * (1.f/17.f));
            }
            #pragma unroll
            for (int d = 21; d < 32; d++) wcb[o*32 + d] = 0;
            bias1f[o] = conv1_b[o] * s1 + sh1;
            float s2 = g2[o] * rsqrtf(v2[o] + EPSF);
            scale2[o] = s2;
            shift2f[o] = conv2_b[o] * s2 + (b2[o] - m2[o] * s2);
        }
    }
    size_t idx = (size_t)blockIdx.x * 256 + threadIdx.x;
    if (idx >= (size_t)NPK_TOT) return;
    if (idx < NPK_X) {
        int s = idx & 511, c = (idx >> 9) & 127, b = idx >> 16;
        float v = (c < CC && s < TT) ? x[((size_t)b * CC + c) * TT + s] : 0.f;
        xb[idx] = f2bf(v);
    } else if (idx < NPK_X + NPK_W) {
        size_t j = idx - NPK_X;
        int s = j & 511, t = (j >> 9) & 511, sub = j >> 18;
        float v = (t < TT && s < TT) ? W_sub[((size_t)sub * TT + t) * TT + s] : 0.f;
        wb[j] = f2bf(v);
    } else if (idx < NPK_X + NPK_W + NPK_W2) {
        size_t j = idx - NPK_X - NPK_W;
        int o  = (int)(j / (WID * CC));
        int r  = (int)(j % (WID * CC));
        int op = r / CC, c = r % CC;
        w2p[(size_t)o * KP + (size_t)c * WID + op] = f2bf(conv2_w[j]);
    } else if (idx < NPK_X + NPK_W + NPK_W2 + NPK_M1) {
        size_t j = idx - NPK_X - NPK_W - NPK_W2;
        w1b[j] = f2bf(mlp1_w[j]);
    } else {
        size_t j = idx - NPK_X - NPK_W - NPK_W2 - NPK_M1;
        w2b[j] = f2bf(mlp2_w[j]);
    }
}

// ---------------- subject einsum via MFMA bf16, B-tile staged in LDS ----------------
// 512 blocks (16 t-tiles x 32 b) x 256 thr. B-tile (32 t-rows x 512 k, 32KB) loaded
// coalesced into LDS once (pad +8 elem/row -> 2-way bank conflict = free); kills the
// 4x-redundant 16-row gathers of the previous version. A fragments stay global
// (wave-private rows, no redundancy).
__global__ __launch_bounds__(256) void k_einsum(const unsigned short* __restrict__ xb,
                                                const unsigned short* __restrict__ wb,
                                                const int* __restrict__ sid,
                                                const float* __restrict__ b_sub,
                                                float* __restrict__ oute) {
    __shared__ unsigned short bt[32 * 520];   // 33.3 KB
    int t0 = blockIdx.x * 32, b = blockIdx.y;
    int s = sid[b];
    int tid = threadIdx.x, w = tid >> 6, lr = tid & 15, lg = (tid >> 4) & 3;
    // stage B rows [t0, t0+32) -- rows 500..511 are zero-padded by k_pack
    {
        const unsigned short* src = wb + (size_t)s * 262144 + (size_t)t0 * 512;
        #pragma unroll
        for (int i = tid; i < 2048; i += 256) {    // 16B chunks
            int row = i >> 6, col8 = i & 63;
            *(u16x8*)(bt + row * 520 + col8 * 8) = *(const u16x8*)(src + row * 512 + col8 * 8);
        }
    }
    __syncthreads();
    const unsigned short* A0 = xb + ((size_t)(b * 128 + w * 32 + lr)) * 512 + 8 * lg;
    f32x4 acc[2][2] = {};
    for (int kb = 0; kb < 512; kb += 32) {
        BF8 a0, a1;
        a0.u = *(const u16x8*)(A0 + kb);
        a1.u = *(const u16x8*)(A0 + 16 * 512 + kb);
        #pragma unroll
        for (int nt = 0; nt < 2; nt++) {
            BF8 bf; bf.u = *(const u16x8*)(bt + (nt * 16 + lr) * 520 + kb + 8 * lg);
            acc[0][nt] = __builtin_amdgcn_mfma_f32_16x16x32_bf16(a0.b, bf.b, acc[0][nt], 0, 0, 0);
            acc[1][nt] = __builtin_amdgcn_mfma_f32_16x16x32_bf16(a1.b, bf.b, acc[1][nt], 0, 0, 0);
        }
    }
    const float* bg = b_sub + (size_t)s * TT;
    #pragma unroll
    for (int nt = 0; nt < 2; nt++) {
        int t = t0 + nt * 16 + lr;
        if (t < TT) {
            float bias = bg[t];
            #pragma unroll
            for (int mt = 0; mt < 2; mt++) {
                int crow = w * 32 + mt * 16 + 4 * lg;
                #pragma unroll
                for (int r = 0; r < 4; r++) {
                    int c = crow + r;
                    if (c < CC) oute[((size_t)b * CC + c) * TT + t] = acc[mt][nt][r] + bias;
                }
            }
        }
    }
}

// ---------------- fused FIR+conv2 (round-0 verbatim) ----------------
__global__ __launch_bounds__(384) void k_fc(const float* __restrict__ oute,
                                            const unsigned short* __restrict__ wcb,
                                            const float* __restrict__ b1f,
                                            const unsigned short* __restrict__ w2p,
                                            float* __restrict__ part) {
    __shared__ float e2[2][512];
    __shared__ unsigned short pt[96][164];
    int chunk = blockIdx.x, b = blockIdx.y;
    int tid = threadIdx.x, w = tid >> 6, l = tid & 63, lr = l & 15, lg = l >> 4;
    BF8 af[5]; float4 bf4[5];
    #pragma unroll
    for (int ot = 0; ot < 5; ot++) {
        af[ot].u = *(const u16x8*)(wcb + (ot * 16 + lr) * 32 + 8 * lg);
        bf4[ot] = *(const float4*)(b1f + ot * 16 + 4 * lg);
    }
    const unsigned short* Arow = w2p + (size_t)lr * KP + 8 * lg;
    f32x4 acc2[5] = {};
    for (int ci = 0; ci < 4; ci++) {
        int cp = chunk * 4 + ci;
        bool live = cp < 61;              // block-uniform
        if (live) {
            if (tid < 250) {
                int cc = tid / 125, i = tid % 125;
                ((float4*)e2[cc])[i] = ((const float4*)(oute + ((size_t)b * CC + cp * 2 + cc) * TT))[i];
            }
            if (tid >= 232 && tid < 256) {   // zero-pad e[500..511] both rows
                int j = tid - 232; int cc = j / 12, i = 500 + (j % 12);
                e2[cc][i] = 0.f;
            }
        }
        __syncthreads();                  // e2 ready; prev-iter pt reads done
        if (live) {
            #pragma unroll
            for (int cc = 0; cc < 2; cc++) {
                int t = w * 16 + lr;
                const float* ew = e2[cc] + 5 * t + 8 * lg;
                BF8 bfr;
                #pragma unroll
                for (int j = 0; j < 8; j++) bfr.u[j] = f2bf(ew[j]);
                f32x4 fa[5] = {};
                #pragma unroll
                for (int ot = 0; ot < 5; ot++)
                    fa[ot] = __builtin_amdgcn_mfma_f32_16x16x32_bf16(af[ot].b, bfr.b, fa[ot], 0, 0, 0);
                #pragma unroll
                for (int ot = 0; ot < 5; ot++) {
                    union { unsigned short s[4]; uint2 v; } pk;
                    #pragma unroll
                    for (int r = 0; r < 4; r++) pk.s[r] = f2bf(eluf(fa[ot][r] + bf4[ot][r]));
                    *(uint2*)&pt[t][cc * 80 + ot * 16 + 4 * lg] = pk.v;
                }
            }
        }
        __syncthreads();                  // pt ready
        if (live) {
            #pragma unroll
            for (int kl = 0; kl < 5; kl++) {
                BF8 bf; bf.u = *(const u16x8*)(&pt[w * 16 + lr][kl * 32 + lg * 8]);
                int ko = cp * 160 + kl * 32;
                #pragma unroll
                for (int mt = 0; mt < 5; mt++) {
                    BF8 a; a.u = *(const u16x8*)(Arow + (size_t)mt * 16 * KP + ko);
                    acc2[mt] = __builtin_amdgcn_mfma_f32_16x16x32_bf16(a.b, bf.b, acc2[mt], 0, 0, 0);
                }
            }
        }
    }
    float* pp = part + ((size_t)(chunk * BB + b) * WID) * TP;
    int t = w * 16 + lr;
    #pragma unroll
    for (int mt = 0; mt < 5; mt++) {
        int ob = mt * 16 + 4 * lg;
        #pragma unroll
        for (int r = 0; r < 4; r++)
            pp[(size_t)(ob + r) * TP + t] = acc2[mt][r];
    }
}

// ---------------- reduce split-K + bn2 + elu + proj -> z_bf (round-3 verbatim) ----------
__global__ __launch_bounds__(256) void k_redproj(const float* __restrict__ part,
                                                 const float* __restrict__ scale2,
                                                 const float* __restrict__ shift2f,
                                                 const float* __restrict__ pw,
                                                 const float* __restrict__ pb,
                                                 unsigned short* __restrict__ zbf) {
    __shared__ float ly[WID * 12];   // 960
    __shared__ float lw[EMB * WID];  // 640
    int tq = blockIdx.x, b = blockIdx.y;
    int tid = threadIdx.x;
    int t0 = tq * 12;
    for (int i = tid; i < EMB * WID; i += 256) lw[i] = pw[i];
    if (tid < 240) {                 // 80 o x 3 float4
        int o = tid / 3, q = tid % 3;
        const float* pbase = part + (size_t)b * (WID * TP) + o * TP + t0 + 4 * q;
        float4 a = {0.f, 0.f, 0.f, 0.f};
        #pragma unroll
        for (int ks = 0; ks < KSPLIT; ks++) {
            float4 v = *(const float4*)(pbase + (size_t)ks * (BB * WID * TP));
            a.x += v.x; a.y += v.y; a.z += v.z; a.w += v.w;
        }
        float sc = scale2[o], sh = shift2f[o];
        ly[o * 12 + 4 * q + 0] = eluf(a.x * sc + sh);
        ly[o * 12 + 4 * q + 1] = eluf(a.y * sc + sh);
        ly[o * 12 + 4 * q + 2] = eluf(a.z * sc + sh);
        ly[o * 12 + 4 * q + 3] = eluf(a.w * sc + sh);
    }
    __syncthreads();
    if (tid < 12 * EMB) {
        int e = tid & 7, tl = tid >> 3;
        float acc = pb[e];
        #pragma unroll 10
        for (int o = 0; o < WID; o++) acc = fmaf(ly[o * 12 + tl], lw[e * WID + o], acc);
        zbf[(size_t)b * HID + (t0 + tl) * EMB + e] = f2bf(acc);
    }
}

// ---------------- mlp1: 128 blocks (64 col-units x 2 row-halves); 4-wave K-split ----
__global__ __launch_bounds__(256) void k_mlp1(const unsigned short* __restrict__ zbf,
                                              const unsigned short* __restrict__ w1b,
                                              const float* __restrict__ bias,
                                              float* __restrict__ z1,
                                              unsigned short* __restrict__ gbf) {
    __shared__ float accb[4][64][4];
    int cu = blockIdx.x >> 1, rh = blockIdx.x & 1;
    int tid = threadIdx.x, w = tid >> 6, l = tid & 63, lr = l & 15, lg = l >> 4;
    int pcol = cu * 16 + lr;
    const unsigned short* wr = w1b + (size_t)pcol * HID + w * 192 + 8 * lg;
    const unsigned short* za = zbf + (size_t)(rh * 16 + lr) * HID + w * 192 + 8 * lg;
    f32x4 acc = {};
    #pragma unroll
    for (int kb = 0; kb < 192; kb += 32) {
        BF8 bf; bf.u = *(const u16x8*)(wr + kb);
        BF8 a;  a.u  = *(const u16x8*)(za + kb);
        acc = __builtin_amdgcn_mfma_f32_16x16x32_bf16(a.b, bf.b, acc, 0, 0, 0);
    }
    #pragma unroll
    for (int r = 0; r < 4; r++) accb[w][l][r] = acc[r];
    __syncthreads();
    if (w == 0) {
        float bs = bias[pcol];
        #pragma unroll
        for (int r = 0; r < 4; r++) {
            int row = rh * 16 + 4 * lg + r;
            float v = bs;
            #pragma unroll
            for (int q = 0; q < 4; q++) v += accb[q][l][r];
            z1[(size_t)row * PROJ + pcol] = v;
            gbf[(size_t)row * PROJ + pcol] = f2bf(0.5f * v * (1.f + erff(v * 0.70710678118654752f)));
        }
    }
}

// ---------------- fused mlp2 + LayerNorm: one block per batch row ----------------
// y[b,:] = z1[b,:] + G[b,:] @ W2^T + b2 computed fully inside one block (VALU dot,
// W2 is L2-resident 2MB), then in-block LN -> out. y never touches HBM; kills the
// separate k_ln dispatch + boundary. 32 blocks x 512 thr (8 waves), 2 cols/thread.
__global__ __launch_bounds__(512) void k_m2ln(const unsigned short* __restrict__ gbf,
                                              const float* __restrict__ z1,
                                              const unsigned short* __restrict__ w2b,
                                              const float* __restrict__ bias,
                                              const float* __restrict__ lngw,
                                              const float* __restrict__ lnbw,
                                              float* __restrict__ out) {
    __shared__ float gv[PROJ];          // G row as f32 (4 KB)
    __shared__ float ss[8], ssq[8];
    __shared__ float smu, sinv;
    int b = blockIdx.x, tid = threadIdx.x;
    // stage + convert G row
    if (tid < 128) {
        u16x8 g = *(const u16x8*)(gbf + (size_t)b * PROJ + tid * 8);
        #pragma unroll
        for (int j = 0; j < 8; j++) gv[tid * 8 + j] = bf2f(g[j]);
    }
    __syncthreads();
    int q1 = tid, q2 = tid + 512;
    const unsigned short* wr1 = w2b + (size_t)q1 * PROJ;
    const unsigned short* wr2 = w2b + (size_t)q2 * PROJ;
    float acc1 = 0.f, acc2 = 0.f;
    #pragma unroll 4
    for (int k = 0; k < PROJ; k += 8) {
        u16x8 wa = *(const u16x8*)(wr1 + k);
        u16x8 wc = *(const u16x8*)(wr2 + k);
        const float* g = gv + k;        // LDS broadcast reads
        #pragma unroll
        for (int j = 0; j < 8; j++) {
            acc1 = fmaf(bf2f(wa[j]), g[j], acc1);
            acc2 = fmaf(bf2f(wc[j]), g[j], acc2);
        }
    }
    float y1 = acc1 + bias[q1] + z1[(size_t)b * PROJ + q1];
    float y2 = acc2 + bias[q2] + z1[(size_t)b * PROJ + q2];
    // block LN over 1024 values (2 per thread)
    float s = y1 + y2, sq = y1 * y1 + y2 * y2;
    #pragma unroll
    for (int off = 32; off > 0; off >>= 1) {
        s  += __shfl_down(s, off);
        sq += __shfl_down(sq, off);
    }
    int wv = tid >> 6, lane = tid & 63;
    if (lane == 0) { ss[wv] = s; ssq[wv] = sq; }
    __syncthreads();
    if (tid == 0) {
        float Sm = 0.f, Sq = 0.f;
        #pragma unroll
        for (int q = 0; q < 8; q++) { Sm += ss[q]; Sq += ssq[q]; }
        float mu = Sm * (1.f / PROJ);
        float var = Sq * (1.f / PROJ) - mu * mu;
        smu = mu;
        sinv = rsqrtf(var + EPSF);
    }
    __syncthreads();
    float mu = smu, inv = sinv;
    out[(size_t)b * PROJ + q1] = (y1 - mu) * inv * lngw[q1] + lnbw[q1];
    out[(size_t)b * PROJ + q2] = (y2 - mu) * inv * lngw[q2] + lnbw[q2];
}

extern "C" void kernel_launch(void* const* d_in, const int* in_sizes, int n_in,
                              void* d_out, int out_size, void* d_ws, size_t ws_size,
                              hipStream_t stream) {
    const float* x        = (const float*)d_in[0];
    const int*   sid      = (const int*)  d_in[1];
    const float* W_sub    = (const float*)d_in[2];
    const float* b_sub    = (const float*)d_in[3];
    const float* conv1_w  = (const float*)d_in[4];
    const float* conv1_b  = (const float*)d_in[5];
    const float* bn1_g    = (const float*)d_in[6];
    const float* bn1_b    = (const float*)d_in[7];
    const float* bn1_m    = (const float*)d_in[8];
    const float* bn1_v    = (const float*)d_in[9];
    const float* conv2_w  = (const float*)d_in[10];
    const float* conv2_b  = (const float*)d_in[11];
    const float* bn2_g    = (const float*)d_in[12];
    const float* bn2_b    = (const float*)d_in[13];
    const float* bn2_m    = (const float*)d_in[14];
    const float* bn2_v    = (const float*)d_in[15];
    const float* proj_w   = (const float*)d_in[16];
    const float* proj_b   = (const float*)d_in[17];
    const float* mlp1_w   = (const float*)d_in[18];
    const float* mlp1_b   = (const float*)d_in[19];
    const float* mlp2_w   = (const float*)d_in[20];
    const float* mlp2_b   = (const float*)d_in[21];
    const float* ln_g     = (const float*)d_in[22];
    const float* ln_b     = (const float*)d_in[23];
    float* out = (float*)d_out;
    float* ws  = (float*)d_ws;

    float* ws_e    = ws + OFF_E;
    unsigned short* ws_xb  = (unsigned short*)(ws + OFF_XB);
    unsigned short* ws_wb  = (unsigned short*)(ws + OFF_WB);
    unsigned short* ws_w2p = (unsigned short*)(ws + OFF_W2P);
    float* ws_part = ws + OFF_PART;
    unsigned short* ws_zbf = (unsigned short*)(ws + OFF_Z);
    float* ws_z1   = ws + OFF_Z1;
    unsigned short* ws_gbf = (unsigned short*)(ws + OFF_G);
    unsigned short* ws_w1b = (unsigned short*)(ws + OFF_W1B);
    unsigned short* ws_w2b = (unsigned short*)(ws + OFF_W2B);
    unsigned short* ws_wcb = (unsigned short*)(ws + OFF_WCB);
    float* ws_b1f  = ws + OFF_B1F;
    float* ws_sc2  = ws + OFF_SC2;
    float* ws_sh2  = ws + OFF_SH2;

    hipLaunchKernelGGL(k_pack, dim3((NPK_TOT + 255) / 256), dim3(256), 0, stream,
                       x, W_sub, conv2_w, mlp1_w, mlp2_w,
                       conv1_w, conv1_b, bn1_g, bn1_b, bn1_m, bn1_v,
                       conv2_b, bn2_g, bn2_b, bn2_m, bn2_v,
                       ws_xb, ws_wb, ws_w2p, ws_w1b, ws_w2b,
                       ws_wcb, ws_b1f, ws_sc2, ws_sh2);

    hipLaunchKernelGGL(k_einsum, dim3(16, BB), dim3(256), 0, stream,
                       ws_xb, ws_wb, sid, b_sub, ws_e);

    hipLaunchKernelGGL(k_fc, dim3(KSPLIT, BB), dim3(384), 0, stream,
                       ws_e, ws_wcb, ws_b1f, ws_w2p, ws_part);

    hipLaunchKernelGGL(k_redproj, dim3(8, BB), dim3(256), 0, stream,
                       ws_part, ws_sc2, ws_sh2, proj_w, proj_b, ws_zbf);

    hipLaunchKernelGGL(k_mlp1, dim3(128), dim3(256), 0, stream,
                       ws_zbf, ws_w1b, mlp1_b, ws_z1, ws_gbf);

    hipLaunchKernelGGL(k_m2ln, dim3(BB), dim3(512), 0, stream,
                       ws_gbf, ws_z1, ws_w2b, mlp2_b, ln_g, ln_b, out);
}

// Round 5
// 199.317 us; speedup vs baseline: 1.2486x; 1.2486x over previous
//
#include <hip/hip_runtime.h>
#include <math.h>

// Problem constants
#define BB 32
#define CC 122
#define TT 500
#define SS 13
#define WID 80
#define EMB 8
#define PROJ 1024
#define HID 768
#define TP 96          // pooled time length
#define EPSF 1e-5f
#define KP 9760        // conv2 flat K' = 122*80
#define KSPLIT 16      // 16 chunks x 4 c-pairs (c-pairs 61..63 are zero/skip)

typedef float f32x4 __attribute__((ext_vector_type(4)));
typedef __bf16 bf16x8 __attribute__((ext_vector_type(8)));
typedef unsigned short u16x8 __attribute__((ext_vector_type(8)));
union BF8 { u16x8 u; bf16x8 b; };

// float -> bf16 bits, round-to-nearest-even
__device__ __forceinline__ unsigned short f2bf(float f) {
    union { float f; unsigned u; } v; v.f = f;
    unsigned r = v.u + 0x7FFFu + ((v.u >> 16) & 1u);
    return (unsigned short)(r >> 16);
}

__device__ __forceinline__ float eluf(float x) {
    return x > 0.f ? x : __expf(x) - 1.f;
}

// ---------------- workspace layout (float offsets) ----------------
#define OFF_E    ((size_t)0)            // oute (B,C,T) bf16 (fits in old f32 region)
#define OFF_XB   ((size_t)1952000)      // x_bf (B,128,512) bf16
#define OFF_W2P  ((size_t)4704512)      // w2p (80,9760) bf16
#define OFF_PART ((size_t)20086272)     // (KSPLIT,B,WID,TP) f32
#define OFF_Z    ((size_t)24018432)     // z_bf (B,HID) bf16
#define OFF_Z1   ((size_t)24030720)     // z1 (B,PROJ) f32
#define OFF_G    ((size_t)24063488)     // g_bf (B,PROJ) bf16
#define OFF_Y    ((size_t)24079872)     // y (B,PROJ) f32
#define OFF_W1B  ((size_t)24112640)     // w1b (PROJ,HID) bf16
#define OFF_W2B  ((size_t)24505856)     // w2b (PROJ,PROJ) bf16
#define OFF_WCB  ((size_t)25030144)     // wcb (80,32) bf16
#define OFF_B1F  ((size_t)25031424)     // (WID)
#define OFF_SC2  ((size_t)25031504)     // (WID)
#define OFF_SH2  ((size_t)25031584)     // (WID)

// pack region sizes (elements) -- W_sub staging removed (einsum converts on the fly)
#define NPK_X  (2097152)   // 32*128*512
#define NPK_W2 (780800)    // 80*9760
#define NPK_M1 (786432)    // 1024*768
#define NPK_M2 (1048576)   // 1024*1024
#define NPK_TOT (NPK_X + NPK_W2 + NPK_M1 + NPK_M2)

// ---------------- pack (bf16 staging) + prep (block 0) ----------------
__global__ __launch_bounds__(256) void k_pack(const float* __restrict__ x,
                                              const float* __restrict__ conv2_w,
                                              const float* __restrict__ mlp1_w,
                                              const float* __restrict__ mlp2_w,
                                              const float* __restrict__ conv1_w, const float* __restrict__ conv1_b,
                                              const float* __restrict__ g1, const float* __restrict__ b1,
                                              const float* __restrict__ m1, const float* __restrict__ v1,
                                              const float* __restrict__ conv2_b, const float* __restrict__ g2,
                                              const float* __restrict__ b2, const float* __restrict__ m2,
                                              const float* __restrict__ v2,
                                              unsigned short* __restrict__ xb,
                                              unsigned short* __restrict__ w2p,
                                              unsigned short* __restrict__ w1b,
                                              unsigned short* __restrict__ w2b,
                                              unsigned short* __restrict__ wcb, float* __restrict__ bias1f,
                                              float* __restrict__ scale2, float* __restrict__ shift2f) {
    if (blockIdx.x == 0) {
        int o = threadIdx.x;
        if (o < WID) {
            float s1 = g1[o] * rsqrtf(v1[o] + EPSF);
            float sh1 = b1[o] - m1[o] * s1;
            #pragma unroll
            for (int d = 0; d < 21; d++) {
                int klo = d - 16; if (klo < 0) klo = 0;
                int khi = d;      if (khi > 4) khi = 4;
                float acc = 0.f;
                for (int k = klo; k <= khi; k++) acc += conv1_w[o*5 + k];
                wcb[o*32 + d] = f2bf(acc * s1 * (1.f/17.f));
            }
            #pragma unroll
            for (int d = 21; d < 32; d++) wcb[o*32 + d] = 0;
            bias1f[o] = conv1_b[o] * s1 + sh1;
            float s2 = g2[o] * rsqrtf(v2[o] + EPSF);
            scale2[o] = s2;
            shift2f[o] = conv2_b[o] * s2 + (b2[o] - m2[o] * s2);
        }
    }
    size_t idx = (size_t)blockIdx.x * 256 + threadIdx.x;
    if (idx >= (size_t)NPK_TOT) return;
    if (idx < NPK_X) {
        int s = idx & 511, c = (idx >> 9) & 127, b = idx >> 16;
        float v = (c < CC && s < TT) ? x[((size_t)b * CC + c) * TT + s] : 0.f;
        xb[idx] = f2bf(v);
    } else if (idx < NPK_X + NPK_W2) {
        size_t j = idx - NPK_X;
        int o  = (int)(j / (WID * CC));
        int r  = (int)(j % (WID * CC));
        int op = r / CC, c = r % CC;
        w2p[(size_t)o * KP + (size_t)c * WID + op] = f2bf(conv2_w[j]);
    } else if (idx < NPK_X + NPK_W2 + NPK_M1) {
        size_t j = idx - NPK_X - NPK_W2;
        w1b[j] = f2bf(mlp1_w[j]);
    } else {
        size_t j = idx - NPK_X - NPK_W2 - NPK_M1;
        w2b[j] = f2bf(mlp2_w[j]);
    }
}

// ---------------- subject einsum via MFMA bf16, B-tile staged from f32 W_sub ----------------
// 512 blocks (16 t-tiles x 32 b) x 256 thr. B-tile (32 t-rows x 512 k) converted
// f32->bf16 during the coalesced LDS stage (same f2bf rounding as the old pack step ->
// bit-identical numerics, but the 20MB wb pack region disappears). Output written as
// bf16 (identical to fc's old f2bf-on-read rounding; halves oute traffic).
__global__ __launch_bounds__(256) void k_einsum(const unsigned short* __restrict__ xb,
                                                const float* __restrict__ W_sub,
                                                const int* __restrict__ sid,
                                                const float* __restrict__ b_sub,
                                                unsigned short* __restrict__ oute) {
    __shared__ unsigned short bt[32 * 520];   // 33.3 KB, +8 pad/row
    int t0 = blockIdx.x * 32, b = blockIdx.y;
    int s = sid[b];
    int tid = threadIdx.x, w = tid >> 6, lr = tid & 15, lg = (tid >> 4) & 3;
    // stage B rows [t0, t0+32) with bounds + convert
    {
        const float* src = W_sub + (size_t)s * (TT * TT);
        for (int i = tid; i < 2048; i += 256) {
            int row = i >> 6;
            int c0  = (i & 63) << 3;
            int rt  = t0 + row;
            union { unsigned short h[8]; uint4 q; } pk;
            if (rt < TT && c0 + 8 <= TT) {
                const float* p = src + (size_t)rt * TT + c0;
                float4 v0 = *(const float4*)p;
                float4 v1 = *(const float4*)(p + 4);
                pk.h[0] = f2bf(v0.x); pk.h[1] = f2bf(v0.y);
                pk.h[2] = f2bf(v0.z); pk.h[3] = f2bf(v0.w);
                pk.h[4] = f2bf(v1.x); pk.h[5] = f2bf(v1.y);
                pk.h[6] = f2bf(v1.z); pk.h[7] = f2bf(v1.w);
            } else {
                const float* p = src + (size_t)rt * TT;
                #pragma unroll
                for (int j = 0; j < 8; j++)
                    pk.h[j] = (rt < TT && c0 + j < TT) ? f2bf(p[c0 + j]) : (unsigned short)0;
            }
            *(uint4*)(&bt[row * 520 + c0]) = pk.q;
        }
    }
    __syncthreads();
    const unsigned short* A0 = xb + ((size_t)(b * 128 + w * 32 + lr)) * 512 + 8 * lg;
    f32x4 acc[2][2] = {};
    for (int kb = 0; kb < 512; kb += 32) {
        BF8 a0, a1;
        a0.u = *(const u16x8*)(A0 + kb);
        a1.u = *(const u16x8*)(A0 + 16 * 512 + kb);
        #pragma unroll
        for (int nt = 0; nt < 2; nt++) {
            BF8 bf; bf.u = *(const u16x8*)(bt + (nt * 16 + lr) * 520 + kb + 8 * lg);
            acc[0][nt] = __builtin_amdgcn_mfma_f32_16x16x32_bf16(a0.b, bf.b, acc[0][nt], 0, 0, 0);
            acc[1][nt] = __builtin_amdgcn_mfma_f32_16x16x32_bf16(a1.b, bf.b, acc[1][nt], 0, 0, 0);
        }
    }
    const float* bg = b_sub + (size_t)s * TT;
    #pragma unroll
    for (int nt = 0; nt < 2; nt++) {
        int t = t0 + nt * 16 + lr;
        if (t < TT) {
            float bias = bg[t];
            #pragma unroll
            for (int mt = 0; mt < 2; mt++) {
                int crow = w * 32 + mt * 16 + 4 * lg;
                #pragma unroll
                for (int r = 0; r < 4; r++) {
                    int c = crow + r;
                    if (c < CC) oute[((size_t)b * CC + c) * TT + t] = f2bf(acc[mt][nt][r] + bias);
                }
            }
        }
    }
}

// ---------------- fused FIR+conv2 (bf16 oute input; otherwise round-0 structure) ----------
__global__ __launch_bounds__(384) void k_fc(const unsigned short* __restrict__ oute,
                                            const unsigned short* __restrict__ wcb,
                                            const float* __restrict__ b1f,
                                            const unsigned short* __restrict__ w2p,
                                            float* __restrict__ part) {
    __shared__ unsigned short e2[2][512];
    __shared__ unsigned short pt[96][164];
    int chunk = blockIdx.x, b = blockIdx.y;
    int tid = threadIdx.x, w = tid >> 6, l = tid & 63, lr = l & 15, lg = l >> 4;
    BF8 af[5]; float4 bf4[5];
    #pragma unroll
    for (int ot = 0; ot < 5; ot++) {
        af[ot].u = *(const u16x8*)(wcb + (ot * 16 + lr) * 32 + 8 * lg);
        bf4[ot] = *(const float4*)(b1f + ot * 16 + 4 * lg);
    }
    const unsigned short* Arow = w2p + (size_t)lr * KP + 8 * lg;
    f32x4 acc2[5] = {};
    for (int ci = 0; ci < 4; ci++) {
        int cp = chunk * 4 + ci;
        bool live = cp < 61;              // block-uniform
        if (live) {
            if (tid < 250) {
                int cc = tid / 125, i = tid % 125;
                ((uint2*)e2[cc])[i] = ((const uint2*)(oute + ((size_t)b * CC + cp * 2 + cc) * TT))[i];
            }
            if (tid >= 232 && tid < 256) {   // zero-pad e[500..511] both rows
                int j = tid - 232; int cc = j / 12, i = 500 + (j % 12);
                e2[cc][i] = 0;
            }
        }
        __syncthreads();                  // e2 ready; prev-iter pt reads done
        if (live) {
            #pragma unroll
            for (int cc = 0; cc < 2; cc++) {
                int t = w * 16 + lr;
                const unsigned short* ew = e2[cc] + 5 * t + 8 * lg;
                BF8 bfr;
                #pragma unroll
                for (int j = 0; j < 8; j++) bfr.u[j] = ew[j];
                f32x4 fa[5] = {};
                #pragma unroll
                for (int ot = 0; ot < 5; ot++)
                    fa[ot] = __builtin_amdgcn_mfma_f32_16x16x32_bf16(af[ot].b, bfr.b, fa[ot], 0, 0, 0);
                #pragma unroll
                for (int ot = 0; ot < 5; ot++) {
                    union { unsigned short s[4]; uint2 v; } pk;
                    #pragma unroll
                    for (int r = 0; r < 4; r++) pk.s[r] = f2bf(eluf(fa[ot][r] + bf4[ot][r]));
                    *(uint2*)&pt[t][cc * 80 + ot * 16 + 4 * lg] = pk.v;
                }
            }
        }
        __syncthreads();                  // pt ready
        if (live) {
            #pragma unroll
            for (int kl = 0; kl < 5; kl++) {
                BF8 bf; bf.u = *(const u16x8*)(&pt[w * 16 + lr][kl * 32 + lg * 8]);
                int ko = cp * 160 + kl * 32;
                #pragma unroll
                for (int mt = 0; mt < 5; mt++) {
                    BF8 a; a.u = *(const u16x8*)(Arow + (size_t)mt * 16 * KP + ko);
                    acc2[mt] = __builtin_amdgcn_mfma_f32_16x16x32_bf16(a.b, bf.b, acc2[mt], 0, 0, 0);
                }
            }
        }
    }
    float* pp = part + ((size_t)(chunk * BB + b) * WID) * TP;
    int t = w * 16 + lr;
    #pragma unroll
    for (int mt = 0; mt < 5; mt++) {
        int ob = mt * 16 + 4 * lg;
        #pragma unroll
        for (int r = 0; r < 4; r++)
            pp[(size_t)(ob + r) * TP + t] = acc2[mt][r];
    }
}

// ---------------- reduce split-K + bn2 + elu + proj -> z_bf (round-3 verbatim) ----------
__global__ __launch_bounds__(256) void k_redproj(const float* __restrict__ part,
                                                 const float* __restrict__ scale2,
                                                 const float* __restrict__ shift2f,
                                                 const float* __restrict__ pw,
                                                 const float* __restrict__ pb,
                                                 unsigned short* __restrict__ zbf) {
    __shared__ float ly[WID * 12];   // 960
    __shared__ float lw[EMB * WID];  // 640
    int tq = blockIdx.x, b = blockIdx.y;
    int tid = threadIdx.x;
    int t0 = tq * 12;
    for (int i = tid; i < EMB * WID; i += 256) lw[i] = pw[i];
    if (tid < 240) {                 // 80 o x 3 float4
        int o = tid / 3, q = tid % 3;
        const float* pbase = part + (size_t)b * (WID * TP) + o * TP + t0 + 4 * q;
        float4 a = {0.f, 0.f, 0.f, 0.f};
        #pragma unroll
        for (int ks = 0; ks < KSPLIT; ks++) {
            float4 v = *(const float4*)(pbase + (size_t)ks * (BB * WID * TP));
            a.x += v.x; a.y += v.y; a.z += v.z; a.w += v.w;
        }
        float sc = scale2[o], sh = shift2f[o];
        ly[o * 12 + 4 * q + 0] = eluf(a.x * sc + sh);
        ly[o * 12 + 4 * q + 1] = eluf(a.y * sc + sh);
        ly[o * 12 + 4 * q + 2] = eluf(a.z * sc + sh);
        ly[o * 12 + 4 * q + 3] = eluf(a.w * sc + sh);
    }
    __syncthreads();
    if (tid < 12 * EMB) {
        int e = tid & 7, tl = tid >> 3;
        float acc = pb[e];
        #pragma unroll 10
        for (int o = 0; o < WID; o++) acc = fmaf(ly[o * 12 + tl], lw[e * WID + o], acc);
        zbf[(size_t)b * HID + (t0 + tl) * EMB + e] = f2bf(acc);
    }
}

// ---------------- mlp1: 128 blocks (64 col-units x 2 row-halves); 4-wave K-split ----
__global__ __launch_bounds__(256) void k_mlp1(const unsigned short* __restrict__ zbf,
                                              const unsigned short* __restrict__ w1b,
                                              const float* __restrict__ bias,
                                              float* __restrict__ z1,
                                              unsigned short* __restrict__ gbf) {
    __shared__ float accb[4][64][4];
    int cu = blockIdx.x >> 1, rh = blockIdx.x & 1;
    int tid = threadIdx.x, w = tid >> 6, l = tid & 63, lr = l & 15, lg = l >> 4;
    int pcol = cu * 16 + lr;
    const unsigned short* wr = w1b + (size_t)pcol * HID + w * 192 + 8 * lg;
    const unsigned short* za = zbf + (size_t)(rh * 16 + lr) * HID + w * 192 + 8 * lg;
    f32x4 acc = {};
    #pragma unroll
    for (int kb = 0; kb < 192; kb += 32) {
        BF8 bf; bf.u = *(const u16x8*)(wr + kb);
        BF8 a;  a.u  = *(const u16x8*)(za + kb);
        acc = __builtin_amdgcn_mfma_f32_16x16x32_bf16(a.b, bf.b, acc, 0, 0, 0);
    }
    #pragma unroll
    for (int r = 0; r < 4; r++) accb[w][l][r] = acc[r];
    __syncthreads();
    if (w == 0) {
        float bs = bias[pcol];
        #pragma unroll
        for (int r = 0; r < 4; r++) {
            int row = rh * 16 + 4 * lg + r;
            float v = bs;
            #pragma unroll
            for (int q = 0; q < 4; q++) v += accb[q][l][r];
            z1[(size_t)row * PROJ + pcol] = v;
            gbf[(size_t)row * PROJ + pcol] = f2bf(0.5f * v * (1.f + erff(v * 0.70710678118654752f)));
        }
    }
}

// ---------------- mlp2: 128 blocks; y = z1 + Gbf @ W2b^T + b2; 4-wave K-split ----
__global__ __launch_bounds__(256) void k_mlp2(const unsigned short* __restrict__ gbf,
                                              const float* __restrict__ z1,
                                              const unsigned short* __restrict__ w2b,
                                              const float* __restrict__ bias,
                                              float* __restrict__ y) {
    __shared__ float accb[4][64][4];
    int cu = blockIdx.x >> 1, rh = blockIdx.x & 1;
    int tid = threadIdx.x, w = tid >> 6, l = tid & 63, lr = l & 15, lg = l >> 4;
    int pc = cu * 16 + lr;
    const unsigned short* wr = w2b + (size_t)pc * PROJ + w * 256 + 8 * lg;
    const unsigned short* ga = gbf + (size_t)(rh * 16 + lr) * PROJ + w * 256 + 8 * lg;
    f32x4 acc = {};
    #pragma unroll
    for (int kb = 0; kb < 256; kb += 32) {
        BF8 bf; bf.u = *(const u16x8*)(wr + kb);
        BF8 a;  a.u  = *(const u16x8*)(ga + kb);
        acc = __builtin_amdgcn_mfma_f32_16x16x32_bf16(a.b, bf.b, acc, 0, 0, 0);
    }
    #pragma unroll
    for (int r = 0; r < 4; r++) accb[w][l][r] = acc[r];
    __syncthreads();
    if (w == 0) {
        float bs = bias[pc];
        #pragma unroll
        for (int r = 0; r < 4; r++) {
            int row = rh * 16 + 4 * lg + r;
            float v = bs + z1[(size_t)row * PROJ + pc];
            #pragma unroll
            for (int q = 0; q < 4; q++) v += accb[q][l][r];
            y[(size_t)row * PROJ + pc] = v;
        }
    }
}

// ---------------- LayerNorm over 1024 per row -> d_out (round-0 verbatim) ----------------
__global__ __launch_bounds__(256) void k_ln(const float* __restrict__ y,
                                            const float* __restrict__ lg,
                                            const float* __restrict__ lb,
                                            float* __restrict__ out) {
    int b = blockIdx.x, tid = threadIdx.x;
    const float4* yr = (const float4*)(y + (size_t)b * PROJ);
    float4 v = yr[tid];
    float s  = v.x + v.y + v.z + v.w;
    float sq = v.x*v.x + v.y*v.y + v.z*v.z + v.w*v.w;
    #pragma unroll
    for (int off = 32; off > 0; off >>= 1) {
        s  += __shfl_down(s, off);
        sq += __shfl_down(sq, off);
    }
    __shared__ float ss[4], ssq[4];
    int wv = tid >> 6, lane = tid & 63;
    if (lane == 0) { ss[wv] = s; ssq[wv] = sq; }
    __syncthreads();
    __shared__ float smu, sinv;
    if (tid == 0) {
        float Sm = ss[0] + ss[1] + ss[2] + ss[3];
        float Sq = ssq[0] + ssq[1] + ssq[2] + ssq[3];
        float mu = Sm * (1.f / PROJ);
        float var = Sq * (1.f / PROJ) - mu * mu;
        smu = mu;
        sinv = rsqrtf(var + EPSF);
    }
    __syncthreads();
    float mu = smu, inv = sinv;
    float4 g4 = ((const float4*)lg)[tid];
    float4 b4 = ((const float4*)lb)[tid];
    float4 o4;
    o4.x = (v.x - mu) * inv * g4.x + b4.x;
    o4.y = (v.y - mu) * inv * g4.y + b4.y;
    o4.z = (v.z - mu) * inv * g4.z + b4.z;
    o4.w = (v.w - mu) * inv * g4.w + b4.w;
    ((float4*)(out + (size_t)b * PROJ))[tid] = o4;
}

extern "C" void kernel_launch(void* const* d_in, const int* in_sizes, int n_in,
                              void* d_out, int out_size, void* d_ws, size_t ws_size,
                              hipStream_t stream) {
    const float* x        = (const float*)d_in[0];
    const int*   sid      = (const int*)  d_in[1];
    const float* W_sub    = (const float*)d_in[2];
    const float* b_sub    = (const float*)d_in[3];
    const float* conv1_w  = (const float*)d_in[4];
    const float* conv1_b  = (const float*)d_in[5];
    const float* bn1_g    = (const float*)d_in[6];
    const float* bn1_b    = (const float*)d_in[7];
    const float* bn1_m    = (const float*)d_in[8];
    const float* bn1_v    = (const float*)d_in[9];
    const float* conv2_w  = (const float*)d_in[10];
    const float* conv2_b  = (const float*)d_in[11];
    const float* bn2_g    = (const float*)d_in[12];
    const float* bn2_b    = (const float*)d_in[13];
    const float* bn2_m    = (const float*)d_in[14];
    const float* bn2_v    = (const float*)d_in[15];
    const float* proj_w   = (const float*)d_in[16];
    const float* proj_b   = (const float*)d_in[17];
    const float* mlp1_w   = (const float*)d_in[18];
    const float* mlp1_b   = (const float*)d_in[19];
    const float* mlp2_w   = (const float*)d_in[20];
    const float* mlp2_b   = (const float*)d_in[21];
    const float* ln_g     = (const float*)d_in[22];
    const float* ln_b     = (const float*)d_in[23];
    float* out = (float*)d_out;
    float* ws  = (float*)d_ws;

    unsigned short* ws_e   = (unsigned short*)(ws + OFF_E);
    unsigned short* ws_xb  = (unsigned short*)(ws + OFF_XB);
    unsigned short* ws_w2p = (unsigned short*)(ws + OFF_W2P);
    float* ws_part = ws + OFF_PART;
    unsigned short* ws_zbf = (unsigned short*)(ws + OFF_Z);
    float* ws_z1   = ws + OFF_Z1;
    unsigned short* ws_gbf = (unsigned short*)(ws + OFF_G);
    float* ws_y    = ws + OFF_Y;
    unsigned short* ws_w1b = (unsigned short*)(ws + OFF_W1B);
    unsigned short* ws_w2b = (unsigned short*)(ws + OFF_W2B);
    unsigned short* ws_wcb = (unsigned short*)(ws + OFF_WCB);
    float* ws_b1f  = ws + OFF_B1F;
    float* ws_sc2  = ws + OFF_SC2;
    float* ws_sh2  = ws + OFF_SH2;

    hipLaunchKernelGGL(k_pack, dim3((NPK_TOT + 255) / 256), dim3(256), 0, stream,
                       x, conv2_w, mlp1_w, mlp2_w,
                       conv1_w, conv1_b, bn1_g, bn1_b, bn1_m, bn1_v,
                       conv2_b, bn2_g, bn2_b, bn2_m, bn2_v,
                       ws_xb, ws_w2p, ws_w1b, ws_w2b,
                       ws_wcb, ws_b1f, ws_sc2, ws_sh2);

    hipLaunchKernelGGL(k_einsum, dim3(16, BB), dim3(256), 0, stream,
                       ws_xb, W_sub, sid, b_sub, ws_e);

    hipLaunchKernelGGL(k_fc, dim3(KSPLIT, BB), dim3(384), 0, stream,
                       ws_e, ws_wcb, ws_b1f, ws_w2p, ws_part);

    hipLaunchKernelGGL(k_redproj, dim3(8, BB), dim3(256), 0, stream,
                       ws_part, ws_sc2, ws_sh2, proj_w, proj_b, ws_zbf);

    hipLaunchKernelGGL(k_mlp1, dim3(128), dim3(256), 0, stream,
                       ws_zbf, ws_w1b, mlp1_b, ws_z1, ws_gbf);

    hipLaunchKernelGGL(k_mlp2, dim3(128), dim3(256), 0, stream,
                       ws_gbf, ws_z1, ws_w2b, mlp2_b, ws_y);

    hipLaunchKernelGGL(k_ln, dim3(BB), dim3(256), 0, stream,
                       ws_y, ln_g, ln_b, out);
}

// Round 6
// 195.318 us; speedup vs baseline: 1.2741x; 1.0205x over previous
//
#include <hip/hip_runtime.h>
#include <math.h>

// Problem constants
#define BB 32
#define CC 122
#define TT 500
#define SS 13
#define WID 80
#define EMB 8
#define PROJ 1024
#define HID 768
#define TP 96          // pooled time length
#define EPSF 1e-5f
#define KP 9760        // conv2 flat K' = 122*80
#define KSPLIT 16      // 16 chunks x 4 c-pairs (c-pairs 61..63 are zero/skip)

typedef float f32x4 __attribute__((ext_vector_type(4)));
typedef __bf16 bf16x8 __attribute__((ext_vector_type(8)));
typedef unsigned short u16x8 __attribute__((ext_vector_type(8)));
union BF8 { u16x8 u; bf16x8 b; };

// float -> bf16 bits, round-to-nearest-even
__device__ __forceinline__ unsigned short f2bf(float f) {
    union { float f; unsigned u; } v; v.f = f;
    unsigned r = v.u + 0x7FFFu + ((v.u >> 16) & 1u);
    return (unsigned short)(r >> 16);
}

__device__ __forceinline__ float eluf(float x) {
    return x > 0.f ? x : __expf(x) - 1.f;
}

// ---------------- workspace layout (float offsets) ----------------
#define OFF_E    ((size_t)0)            // oute (B,C,T) bf16
#define OFF_XB   ((size_t)1952000)      // x_bf (B,128,512) bf16
#define OFF_W2P  ((size_t)4704512)      // w2p (80,9760) bf16
#define OFF_PART ((size_t)20086272)     // (KSPLIT,B,WID,TP) f32
#define OFF_Z    ((size_t)24018432)     // z_bf (B,HID) bf16
#define OFF_Z1   ((size_t)24030720)     // z1 (B,PROJ) f32
#define OFF_G    ((size_t)24063488)     // g_bf (B,PROJ) bf16
#define OFF_Y    ((size_t)24079872)     // y (B,PROJ) f32
#define OFF_W1B  ((size_t)24112640)     // w1b (PROJ,HID) bf16
#define OFF_W2B  ((size_t)24505856)     // w2b (PROJ,PROJ) bf16
#define OFF_WCB  ((size_t)25030144)     // wcb (80,32) bf16
#define OFF_B1F  ((size_t)25031424)     // (WID)
#define OFF_SC2  ((size_t)25031504)     // (WID)
#define OFF_SH2  ((size_t)25031584)     // (WID)

// pack linear region (w2p handled by dedicated transpose blocks)
#define NPK_X  (2097152)   // 32*128*512
#define NPK_M1 (786432)    // 1024*768
#define NPK_M2 (1048576)   // 1024*1024
#define NPK_LIN (NPK_X + NPK_M1 + NPK_M2)

// ---------------- pack: w2p LDS-transpose (blocks 0..79) + linear bf16 staging ----------
// w2p write was a 64-lane x 160B-stride 2B scatter (worst case); now: coalesced f32
// read -> LDS [80][124] bf16 -> fully coalesced 16B uint4 writes.
__global__ __launch_bounds__(256) void k_pack(const float* __restrict__ x,
                                              const float* __restrict__ conv2_w,
                                              const float* __restrict__ mlp1_w,
                                              const float* __restrict__ mlp2_w,
                                              const float* __restrict__ conv1_w, const float* __restrict__ conv1_b,
                                              const float* __restrict__ g1, const float* __restrict__ b1,
                                              const float* __restrict__ m1, const float* __restrict__ v1,
                                              const float* __restrict__ conv2_b, const float* __restrict__ g2,
                                              const float* __restrict__ b2, const float* __restrict__ m2,
                                              const float* __restrict__ v2,
                                              unsigned short* __restrict__ xb,
                                              unsigned short* __restrict__ w2p,
                                              unsigned short* __restrict__ w1b,
                                              unsigned short* __restrict__ w2b,
                                              unsigned short* __restrict__ wcb, float* __restrict__ bias1f,
                                              float* __restrict__ scale2, float* __restrict__ shift2f) {
    __shared__ unsigned short lt[WID][124];   // 19.8 KB (op-major source tile)
    int bid = blockIdx.x, tid = threadIdx.x;
    if (bid < WID) {
        if (bid == 0 && tid < WID) {
            int o = tid;
            float s1 = g1[o] * rsqrtf(v1[o] + EPSF);
            float sh1 = b1[o] - m1[o] * s1;
            #pragma unroll
            for (int d = 0; d < 21; d++) {
                int klo = d - 16; if (klo < 0) klo = 0;
                int khi = d;      if (khi > 4) khi = 4;
                float acc = 0.f;
                for (int k = klo; k <= khi; k++) acc += conv1_w[o*5 + k];
                wcb[o*32 + d] = f2bf(acc * s1 * (1.f/17.f));
            }
            #pragma unroll
            for (int d = 21; d < 32; d++) wcb[o*32 + d] = 0;
            bias1f[o] = conv1_b[o] * s1 + sh1;
            float s2 = g2[o] * rsqrtf(v2[o] + EPSF);
            scale2[o] = s2;
            shift2f[o] = conv2_b[o] * s2 + (b2[o] - m2[o] * s2);
        }
        // transpose one output unit o: conv2_w[o][op][c] -> w2p[o][c*80+op]
        int o = bid;
        const float* src = conv2_w + (size_t)o * (WID * CC);
        for (int i = tid; i < WID * CC; i += 256) {
            int op = i / CC, c = i - op * CC;
            lt[op][c] = f2bf(src[i]);
        }
        __syncthreads();
        unsigned short* dst = w2p + (size_t)o * KP;
        for (int j = tid; j < KP / 8; j += 256) {
            int k0 = j * 8;
            union { unsigned short h[8]; uint4 q; } pk;
            #pragma unroll
            for (int u = 0; u < 8; u++) {
                int k = k0 + u;
                pk.h[u] = lt[k % WID][k / WID];
            }
            *(uint4*)(dst + k0) = pk.q;
        }
        return;
    }
    size_t idx = (size_t)(bid - WID) * 256 + tid;
    if (idx >= (size_t)NPK_LIN) return;
    if (idx < NPK_X) {
        int s = idx & 511, c = (idx >> 9) & 127, b = idx >> 16;
        float v = (c < CC && s < TT) ? x[((size_t)b * CC + c) * TT + s] : 0.f;
        xb[idx] = f2bf(v);
    } else if (idx < NPK_X + NPK_M1) {
        size_t j = idx - NPK_X;
        w1b[j] = f2bf(mlp1_w[j]);
    } else {
        size_t j = idx - NPK_X - NPK_M1;
        w2b[j] = f2bf(mlp2_w[j]);
    }
}

// ---------------- subject einsum via MFMA bf16, B-tile staged from f32 W_sub (r5 verbatim) --
__global__ __launch_bounds__(256) void k_einsum(const unsigned short* __restrict__ xb,
                                                const float* __restrict__ W_sub,
                                                const int* __restrict__ sid,
                                                const float* __restrict__ b_sub,
                                                unsigned short* __restrict__ oute) {
    __shared__ unsigned short bt[32 * 520];   // 33.3 KB, +8 pad/row
    int t0 = blockIdx.x * 32, b = blockIdx.y;
    int s = sid[b];
    int tid = threadIdx.x, w = tid >> 6, lr = tid & 15, lg = (tid >> 4) & 3;
    {
        const float* src = W_sub + (size_t)s * (TT * TT);
        for (int i = tid; i < 2048; i += 256) {
            int row = i >> 6;
            int c0  = (i & 63) << 3;
            int rt  = t0 + row;
            union { unsigned short h[8]; uint4 q; } pk;
            if (rt < TT && c0 + 8 <= TT) {
                const float* p = src + (size_t)rt * TT + c0;
                float4 v0 = *(const float4*)p;
                float4 v1 = *(const float4*)(p + 4);
                pk.h[0] = f2bf(v0.x); pk.h[1] = f2bf(v0.y);
                pk.h[2] = f2bf(v0.z); pk.h[3] = f2bf(v0.w);
                pk.h[4] = f2bf(v1.x); pk.h[5] = f2bf(v1.y);
                pk.h[6] = f2bf(v1.z); pk.h[7] = f2bf(v1.w);
            } else {
                const float* p = src + (size_t)rt * TT;
                #pragma unroll
                for (int j = 0; j < 8; j++)
                    pk.h[j] = (rt < TT && c0 + j < TT) ? f2bf(p[c0 + j]) : (unsigned short)0;
            }
            *(uint4*)(&bt[row * 520 + c0]) = pk.q;
        }
    }
    __syncthreads();
    const unsigned short* A0 = xb + ((size_t)(b * 128 + w * 32 + lr)) * 512 + 8 * lg;
    f32x4 acc[2][2] = {};
    for (int kb = 0; kb < 512; kb += 32) {
        BF8 a0, a1;
        a0.u = *(const u16x8*)(A0 + kb);
        a1.u = *(const u16x8*)(A0 + 16 * 512 + kb);
        #pragma unroll
        for (int nt = 0; nt < 2; nt++) {
            BF8 bf; bf.u = *(const u16x8*)(bt + (nt * 16 + lr) * 520 + kb + 8 * lg);
            acc[0][nt] = __builtin_amdgcn_mfma_f32_16x16x32_bf16(a0.b, bf.b, acc[0][nt], 0, 0, 0);
            acc[1][nt] = __builtin_amdgcn_mfma_f32_16x16x32_bf16(a1.b, bf.b, acc[1][nt], 0, 0, 0);
        }
    }
    const float* bg = b_sub + (size_t)s * TT;
    #pragma unroll
    for (int nt = 0; nt < 2; nt++) {
        int t = t0 + nt * 16 + lr;
        if (t < TT) {
            float bias = bg[t];
            #pragma unroll
            for (int mt = 0; mt < 2; mt++) {
                int crow = w * 32 + mt * 16 + 4 * lg;
                #pragma unroll
                for (int r = 0; r < 4; r++) {
                    int c = crow + r;
                    if (c < CC) oute[((size_t)b * CC + c) * TT + t] = f2bf(acc[mt][nt][r] + bias);
                }
            }
        }
    }
}

// ---------------- fused FIR+conv2, conv weights staged in LDS ----------------
// Replaces 25 scattered 16B L2 gathers per wave per ci with one coalesced 25.6KB
// stage + ds_read_b128 fragments. 3 barriers/ci (aw overwrite hazard). LDS 60.4KB
// -> 2 blocks/CU (grid is 2/CU anyway).
__global__ __launch_bounds__(384) void k_fc(const unsigned short* __restrict__ oute,
                                            const unsigned short* __restrict__ wcb,
                                            const float* __restrict__ b1f,
                                            const unsigned short* __restrict__ w2p,
                                            float* __restrict__ part) {
    __shared__ unsigned short e2[2][512];          // 2 KB
    __shared__ unsigned short pt[96][164];         // 31.5 KB
    __shared__ unsigned short aw[WID][168];        // 26.9 KB (160 + 8 pad)
    int chunk = blockIdx.x, b = blockIdx.y;
    int tid = threadIdx.x, w = tid >> 6, l = tid & 63, lr = l & 15, lg = l >> 4;
    BF8 af[5]; float4 bf4[5];
    #pragma unroll
    for (int ot = 0; ot < 5; ot++) {
        af[ot].u = *(const u16x8*)(wcb + (ot * 16 + lr) * 32 + 8 * lg);
        bf4[ot] = *(const float4*)(b1f + ot * 16 + 4 * lg);
    }
    f32x4 acc2[5] = {};
    for (int ci = 0; ci < 4; ci++) {
        int cp = chunk * 4 + ci;
        bool live = cp < 61;              // block-uniform
        __syncthreads();                  // prev-iter pt+aw reads done
        if (live) {
            if (tid < 250) {
                int cc = tid / 125, i = tid % 125;
                ((uint2*)e2[cc])[i] = ((const uint2*)(oute + ((size_t)b * CC + cp * 2 + cc) * TT))[i];
            }
            if (tid >= 232 && tid < 256) {   // zero-pad e[500..511] both rows
                int j = tid - 232; int cc = j / 12, i = 500 + (j % 12);
                e2[cc][i] = 0;
            }
            // stage this ci's conv-weight slab: 80 rows x 160 cols bf16, coalesced
            const unsigned short* wsrc = w2p + (size_t)cp * 160;
            for (int i = tid; i < WID * 20; i += 384) {
                int o = i / 20, c8 = i - o * 20;
                *(u16x8*)(&aw[o][c8 * 8]) = *(const u16x8*)(wsrc + (size_t)o * KP + c8 * 8);
            }
        }
        __syncthreads();                  // e2 + aw ready
        if (live) {
            #pragma unroll
            for (int cc = 0; cc < 2; cc++) {
                int t = w * 16 + lr;
                const unsigned short* ew = e2[cc] + 5 * t + 8 * lg;
                BF8 bfr;
                #pragma unroll
                for (int j = 0; j < 8; j++) bfr.u[j] = ew[j];
                f32x4 fa[5] = {};
                #pragma unroll
                for (int ot = 0; ot < 5; ot++)
                    fa[ot] = __builtin_amdgcn_mfma_f32_16x16x32_bf16(af[ot].b, bfr.b, fa[ot], 0, 0, 0);
                #pragma unroll
                for (int ot = 0; ot < 5; ot++) {
                    union { unsigned short s[4]; uint2 v; } pk;
                    #pragma unroll
                    for (int r = 0; r < 4; r++) pk.s[r] = f2bf(eluf(fa[ot][r] + bf4[ot][r]));
                    *(uint2*)&pt[t][cc * 80 + ot * 16 + 4 * lg] = pk.v;
                }
            }
        }
        __syncthreads();                  // pt ready
        if (live) {
            #pragma unroll
            for (int kl = 0; kl < 5; kl++) {
                BF8 bf; bf.u = *(const u16x8*)(&pt[w * 16 + lr][kl * 32 + lg * 8]);
                #pragma unroll
                for (int mt = 0; mt < 5; mt++) {
                    BF8 a; a.u = *(const u16x8*)(&aw[mt * 16 + lr][kl * 32 + lg * 8]);
                    acc2[mt] = __builtin_amdgcn_mfma_f32_16x16x32_bf16(a.b, bf.b, acc2[mt], 0, 0, 0);
                }
            }
        }
    }
    float* pp = part + ((size_t)(chunk * BB + b) * WID) * TP;
    int t = w * 16 + lr;
    #pragma unroll
    for (int mt = 0; mt < 5; mt++) {
        int ob = mt * 16 + 4 * lg;
        #pragma unroll
        for (int r = 0; r < 4; r++)
            pp[(size_t)(ob + r) * TP + t] = acc2[mt][r];
    }
}

// ---------------- reduce split-K + bn2 + elu + proj -> z_bf (r3 verbatim) ----------
__global__ __launch_bounds__(256) void k_redproj(const float* __restrict__ part,
                                                 const float* __restrict__ scale2,
                                                 const float* __restrict__ shift2f,
                                                 const float* __restrict__ pw,
                                                 const float* __restrict__ pb,
                                                 unsigned short* __restrict__ zbf) {
    __shared__ float ly[WID * 12];   // 960
    __shared__ float lw[EMB * WID];  // 640
    int tq = blockIdx.x, b = blockIdx.y;
    int tid = threadIdx.x;
    int t0 = tq * 12;
    for (int i = tid; i < EMB * WID; i += 256) lw[i] = pw[i];
    if (tid < 240) {                 // 80 o x 3 float4
        int o = tid / 3, q = tid % 3;
        const float* pbase = part + (size_t)b * (WID * TP) + o * TP + t0 + 4 * q;
        float4 a = {0.f, 0.f, 0.f, 0.f};
        #pragma unroll
        for (int ks = 0; ks < KSPLIT; ks++) {
            float4 v = *(const float4*)(pbase + (size_t)ks * (BB * WID * TP));
            a.x += v.x; a.y += v.y; a.z += v.z; a.w += v.w;
        }
        float sc = scale2[o], sh = shift2f[o];
        ly[o * 12 + 4 * q + 0] = eluf(a.x * sc + sh);
        ly[o * 12 + 4 * q + 1] = eluf(a.y * sc + sh);
        ly[o * 12 + 4 * q + 2] = eluf(a.z * sc + sh);
        ly[o * 12 + 4 * q + 3] = eluf(a.w * sc + sh);
    }
    __syncthreads();
    if (tid < 12 * EMB) {
        int e = tid & 7, tl = tid >> 3;
        float acc = pb[e];
        #pragma unroll 10
        for (int o = 0; o < WID; o++) acc = fmaf(ly[o * 12 + tl], lw[e * WID + o], acc);
        zbf[(size_t)b * HID + (t0 + tl) * EMB + e] = f2bf(acc);
    }
}

// ---------------- mlp1: 128 blocks (64 col-units x 2 row-halves); 4-wave K-split ----
__global__ __launch_bounds__(256) void k_mlp1(const unsigned short* __restrict__ zbf,
                                              const unsigned short* __restrict__ w1b,
                                              const float* __restrict__ bias,
                                              float* __restrict__ z1,
                                              unsigned short* __restrict__ gbf) {
    __shared__ float accb[4][64][4];
    int cu = blockIdx.x >> 1, rh = blockIdx.x & 1;
    int tid = threadIdx.x, w = tid >> 6, l = tid & 63, lr = l & 15, lg = l >> 4;
    int pcol = cu * 16 + lr;
    const unsigned short* wr = w1b + (size_t)pcol * HID + w * 192 + 8 * lg;
    const unsigned short* za = zbf + (size_t)(rh * 16 + lr) * HID + w * 192 + 8 * lg;
    f32x4 acc = {};
    #pragma unroll
    for (int kb = 0; kb < 192; kb += 32) {
        BF8 bf; bf.u = *(const u16x8*)(wr + kb);
        BF8 a;  a.u  = *(const u16x8*)(za + kb);
        acc = __builtin_amdgcn_mfma_f32_16x16x32_bf16(a.b, bf.b, acc, 0, 0, 0);
    }
    #pragma unroll
    for (int r = 0; r < 4; r++) accb[w][l][r] = acc[r];
    __syncthreads();
    if (w == 0) {
        float bs = bias[pcol];
        #pragma unroll
        for (int r = 0; r < 4; r++) {
            int row = rh * 16 + 4 * lg + r;
            float v = bs;
            #pragma unroll
            for (int q = 0; q < 4; q++) v += accb[q][l][r];
            z1[(size_t)row * PROJ + pcol] = v;
            gbf[(size_t)row * PROJ + pcol] = f2bf(0.5f * v * (1.f + erff(v * 0.70710678118654752f)));
        }
    }
}

// ---------------- mlp2: 128 blocks; y = z1 + Gbf @ W2b^T + b2; 4-wave K-split ----
__global__ __launch_bounds__(256) void k_mlp2(const unsigned short* __restrict__ gbf,
                                              const float* __restrict__ z1,
                                              const unsigned short* __restrict__ w2b,
                                              const float* __restrict__ bias,
                                              float* __restrict__ y) {
    __shared__ float accb[4][64][4];
    int cu = blockIdx.x >> 1, rh = blockIdx.x & 1;
    int tid = threadIdx.x, w = tid >> 6, l = tid & 63, lr = l & 15, lg = l >> 4;
    int pc = cu * 16 + lr;
    const unsigned short* wr = w2b + (size_t)pc * PROJ + w * 256 + 8 * lg;
    const unsigned short* ga = gbf + (size_t)(rh * 16 + lr) * PROJ + w * 256 + 8 * lg;
    f32x4 acc = {};
    #pragma unroll
    for (int kb = 0; kb < 256; kb += 32) {
        BF8 bf; bf.u = *(const u16x8*)(wr + kb);
        BF8 a;  a.u  = *(const u16x8*)(ga + kb);
        acc = __builtin_amdgcn_mfma_f32_16x16x32_bf16(a.b, bf.b, acc, 0, 0, 0);
    }
    #pragma unroll
    for (int r = 0; r < 4; r++) accb[w][l][r] = acc[r];
    __syncthreads();
    if (w == 0) {
        float bs = bias[pc];
        #pragma unroll
        for (int r = 0; r < 4; r++) {
            int row = rh * 16 + 4 * lg + r;
            float v = bs + z1[(size_t)row * PROJ + pc];
            #pragma unroll
            for (int q = 0; q < 4; q++) v += accb[q][l][r];
            y[(size_t)row * PROJ + pc] = v;
        }
    }
}

// ---------------- LayerNorm over 1024 per row -> d_out (r0 verbatim) ----------------
__global__ __launch_bounds__(256) void k_ln(const float* __restrict__ y,
                                            const float* __restrict__ lg,
                                            const float* __restrict__ lb,
                                            float* __restrict__ out) {
    int b = blockIdx.x, tid = threadIdx.x;
    const float4* yr = (const float4*)(y + (size_t)b * PROJ);
    float4 v = yr[tid];
    float s  = v.x + v.y + v.z + v.w;
    float sq = v.x*v.x + v.y*v.y + v.z*v.z + v.w*v.w;
    #pragma unroll
    for (int off = 32; off > 0; off >>= 1) {
        s  += __shfl_down(s, off);
        sq += __shfl_down(sq, off);
    }
    __shared__ float ss[4], ssq[4];
    int wv = tid >> 6, lane = tid & 63;
    if (lane == 0) { ss[wv] = s; ssq[wv] = sq; }
    __syncthreads();
    __shared__ float smu, sinv;
    if (tid == 0) {
        float Sm = ss[0] + ss[1] + ss[2] + ss[3];
        float Sq = ssq[0] + ssq[1] + ssq[2] + ssq[3];
        float mu = Sm * (1.f / PROJ);
        float var = Sq * (1.f / PROJ) - mu * mu;
        smu = mu;
        sinv = rsqrtf(var + EPSF);
    }
    __syncthreads();
    float mu = smu, inv = sinv;
    float4 g4 = ((const float4*)lg)[tid];
    float4 b4 = ((const float4*)lb)[tid];
    float4 o4;
    o4.x = (v.x - mu) * inv * g4.x + b4.x;
    o4.y = (v.y - mu) * inv * g4.y + b4.y;
    o4.z = (v.z - mu) * inv * g4.z + b4.z;
    o4.w = (v.w - mu) * inv * g4.w + b4.w;
    ((float4*)(out + (size_t)b * PROJ))[tid] = o4;
}

extern "C" void kernel_launch(void* const* d_in, const int* in_sizes, int n_in,
                              void* d_out, int out_size, void* d_ws, size_t ws_size,
                              hipStream_t stream) {
    const float* x        = (const float*)d_in[0];
    const int*   sid      = (const int*)  d_in[1];
    const float* W_sub    = (const float*)d_in[2];
    const float* b_sub    = (const float*)d_in[3];
    const float* conv1_w  = (const float*)d_in[4];
    const float* conv1_b  = (const float*)d_in[5];
    const float* bn1_g    = (const float*)d_in[6];
    const float* bn1_b    = (const float*)d_in[7];
    const float* bn1_m    = (const float*)d_in[8];
    const float* bn1_v    = (const float*)d_in[9];
    const float* conv2_w  = (const float*)d_in[10];
    const float* conv2_b  = (const float*)d_in[11];
    const float* bn2_g    = (const float*)d_in[12];
    const float* bn2_b    = (const float*)d_in[13];
    const float* bn2_m    = (const float*)d_in[14];
    const float* bn2_v    = (const float*)d_in[15];
    const float* proj_w   = (const float*)d_in[16];
    const float* proj_b   = (const float*)d_in[17];
    const float* mlp1_w   = (const float*)d_in[18];
    const float* mlp1_b   = (const float*)d_in[19];
    const float* mlp2_w   = (const float*)d_in[20];
    const float* mlp2_b   = (const float*)d_in[21];
    const float* ln_g     = (const float*)d_in[22];
    const float* ln_b     = (const float*)d_in[23];
    float* out = (float*)d_out;
    float* ws  = (float*)d_ws;

    unsigned short* ws_e   = (unsigned short*)(ws + OFF_E);
    unsigned short* ws_xb  = (unsigned short*)(ws + OFF_XB);
    unsigned short* ws_w2p = (unsigned short*)(ws + OFF_W2P);
    float* ws_part = ws + OFF_PART;
    unsigned short* ws_zbf = (unsigned short*)(ws + OFF_Z);
    float* ws_z1   = ws + OFF_Z1;
    unsigned short* ws_gbf = (unsigned short*)(ws + OFF_G);
    float* ws_y    = ws + OFF_Y;
    unsigned short* ws_w1b = (unsigned short*)(ws + OFF_W1B);
    unsigned short* ws_w2b = (unsigned short*)(ws + OFF_W2B);
    unsigned short* ws_wcb = (unsigned short*)(ws + OFF_WCB);
    float* ws_b1f  = ws + OFF_B1F;
    float* ws_sc2  = ws + OFF_SC2;
    float* ws_sh2  = ws + OFF_SH2;

    hipLaunchKernelGGL(k_pack, dim3(WID + (NPK_LIN + 255) / 256), dim3(256), 0, stream,
                       x, conv2_w, mlp1_w, mlp2_w,
                       conv1_w, conv1_b, bn1_g, bn1_b, bn1_m, bn1_v,
                       conv2_b, bn2_g, bn2_b, bn2_m, bn2_v,
                       ws_xb, ws_w2p, ws_w1b, ws_w2b,
                       ws_wcb, ws_b1f, ws_sc2, ws_sh2);

    hipLaunchKernelGGL(k_einsum, dim3(16, BB), dim3(256), 0, stream,
                       ws_xb, W_sub, sid, b_sub, ws_e);

    hipLaunchKernelGGL(k_fc, dim3(KSPLIT, BB), dim3(384), 0, stream,
                       ws_e, ws_wcb, ws_b1f, ws_w2p, ws_part);

    hipLaunchKernelGGL(k_redproj, dim3(8, BB), dim3(256), 0, stream,
                       ws_part, ws_sc2, ws_sh2, proj_w, proj_b, ws_zbf);

    hipLaunchKernelGGL(k_mlp1, dim3(128), dim3(256), 0, stream,
                       ws_zbf, ws_w1b, mlp1_b, ws_z1, ws_gbf);

    hipLaunchKernelGGL(k_mlp2, dim3(128), dim3(256), 0, stream,
                       ws_gbf, ws_z1, ws_w2b, mlp2_b, ws_y);

    hipLaunchKernelGGL(k_ln, dim3(BB), dim3(256), 0, stream,
                       ws_y, ln_g, ln_b, out);
}

// Round 7
// 192.981 us; speedup vs baseline: 1.2896x; 1.0121x over previous
//
#include <hip/hip_runtime.h>
#include <math.h>

// Problem constants
#define BB 32
#define CC 122
#define TT 500
#define SS 13
#define WID 80
#define EMB 8
#define PROJ 1024
#define HID 768
#define TP 96          // pooled time length
#define EPSF 1e-5f
#define KP 9760        // conv2 flat K' = 122*80
#define KSPLIT 16      // 16 chunks x 4 c-pairs (c-pairs 61..63 are zero/skip)

typedef float f32x4 __attribute__((ext_vector_type(4)));
typedef __bf16 bf16x8 __attribute__((ext_vector_type(8)));
typedef unsigned short u16x8 __attribute__((ext_vector_type(8)));
union BF8 { u16x8 u; bf16x8 b; };

// float -> bf16 bits, round-to-nearest-even
__device__ __forceinline__ unsigned short f2bf(float f) {
    union { float f; unsigned u; } v; v.f = f;
    unsigned r = v.u + 0x7FFFu + ((v.u >> 16) & 1u);
    return (unsigned short)(r >> 16);
}

__device__ __forceinline__ float eluf(float x) {
    return x > 0.f ? x : __expf(x) - 1.f;
}

// ---------------- workspace layout (float offsets) ----------------
#define OFF_E    ((size_t)0)            // oute (B,C,T) bf16
#define OFF_XB   ((size_t)1952000)      // xa swizzled A-fragments (B,8,16,64,8) bf16
#define OFF_W2P  ((size_t)4704512)      // w2p (80,9760) bf16
#define OFF_PART ((size_t)20086272)     // (KSPLIT,B,WID,TP) f32
#define OFF_Z    ((size_t)24018432)     // z_bf (B,HID) bf16
#define OFF_Z1   ((size_t)24030720)     // z1 (B,PROJ) f32
#define OFF_G    ((size_t)24063488)     // g_bf (B,PROJ) bf16
#define OFF_Y    ((size_t)24079872)     // y (B,PROJ) f32
#define OFF_W1B  ((size_t)24112640)     // w1b (PROJ,HID) bf16
#define OFF_W2B  ((size_t)24505856)     // w2b (PROJ,PROJ) bf16
#define OFF_WCB  ((size_t)25030144)     // wcb (80,32) bf16
#define OFF_B1F  ((size_t)25031424)     // (WID)
#define OFF_SC2  ((size_t)25031504)     // (WID)
#define OFF_SH2  ((size_t)25031584)     // (WID)

// pack linear region (w2p handled by dedicated transpose blocks)
#define NPK_X  (2097152)   // 32*8*16*64*8  (same count, swizzled layout)
#define NPK_M1 (786432)    // 1024*768
#define NPK_M2 (1048576)   // 1024*1024
#define NPK_LIN (NPK_X + NPK_M1 + NPK_M2)

// ---------------- pack: w2p LDS-transpose (blocks 0..79) + linear bf16 staging ----------
// xa layout: [b][sp][kk][lane][8] -- tile (sp,kk) is the exact 16x32 MFMA A-fragment
// in lane order (lane = lg*16+lr; element (row = sp*16+lr, col = kk*32 + lg*8 + u)).
// einsum's A loads become single coalesced 1KB wave transactions (was a 16-row gather).
__global__ __launch_bounds__(256) void k_pack(const float* __restrict__ x,
                                              const float* __restrict__ conv2_w,
                                              const float* __restrict__ mlp1_w,
                                              const float* __restrict__ mlp2_w,
                                              const float* __restrict__ conv1_w, const float* __restrict__ conv1_b,
                                              const float* __restrict__ g1, const float* __restrict__ b1,
                                              const float* __restrict__ m1, const float* __restrict__ v1,
                                              const float* __restrict__ conv2_b, const float* __restrict__ g2,
                                              const float* __restrict__ b2, const float* __restrict__ m2,
                                              const float* __restrict__ v2,
                                              unsigned short* __restrict__ xb,
                                              unsigned short* __restrict__ w2p,
                                              unsigned short* __restrict__ w1b,
                                              unsigned short* __restrict__ w2b,
                                              unsigned short* __restrict__ wcb, float* __restrict__ bias1f,
                                              float* __restrict__ scale2, float* __restrict__ shift2f) {
    __shared__ unsigned short lt[WID][124];   // 19.8 KB (op-major source tile)
    int bid = blockIdx.x, tid = threadIdx.x;
    if (bid < WID) {
        if (bid == 0 && tid < WID) {
            int o = tid;
            float s1 = g1[o] * rsqrtf(v1[o] + EPSF);
            float sh1 = b1[o] - m1[o] * s1;
            #pragma unroll
            for (int d = 0; d < 21; d++) {
                int klo = d - 16; if (klo < 0) klo = 0;
                int khi = d;      if (khi > 4) khi = 4;
                float acc = 0.f;
                for (int k = klo; k <= khi; k++) acc += conv1_w[o*5 + k];
                wcb[o*32 + d] = f2bf(acc * s1 * (1.f/17.f));
            }
            #pragma unroll
            for (int d = 21; d < 32; d++) wcb[o*32 + d] = 0;
            bias1f[o] = conv1_b[o] * s1 + sh1;
            float s2 = g2[o] * rsqrtf(v2[o] + EPSF);
            scale2[o] = s2;
            shift2f[o] = conv2_b[o] * s2 + (b2[o] - m2[o] * s2);
        }
        // transpose one output unit o: conv2_w[o][op][c] -> w2p[o][c*80+op]
        int o = bid;
        const float* src = conv2_w + (size_t)o * (WID * CC);
        for (int i = tid; i < WID * CC; i += 256) {
            int op = i / CC, c = i - op * CC;
            lt[op][c] = f2bf(src[i]);
        }
        __syncthreads();
        unsigned short* dst = w2p + (size_t)o * KP;
        for (int j = tid; j < KP / 8; j += 256) {
            int k0 = j * 8;
            union { unsigned short h[8]; uint4 q; } pk;
            #pragma unroll
            for (int u = 0; u < 8; u++) {
                int k = k0 + u;
                pk.h[u] = lt[k % WID][k / WID];
            }
            *(uint4*)(dst + k0) = pk.q;
        }
        return;
    }
    size_t idx = (size_t)(bid - WID) * 256 + tid;
    if (idx >= (size_t)NPK_LIN) return;
    if (idx < NPK_X) {
        // decode swizzled position: idx = (((b*8+sp)*16+kk)*64 + l)*8 + u
        int u = (int)(idx & 7);
        size_t j = idx >> 3;
        int l  = (int)(j & 63); j >>= 6;
        int kk = (int)(j & 15); j >>= 4;
        int sp = (int)(j & 7);
        int b  = (int)(j >> 3);
        int c  = sp * 16 + (l & 15);
        int s  = kk * 32 + (l >> 4) * 8 + u;
        float v = (c < CC && s < TT) ? x[((size_t)b * CC + c) * TT + s] : 0.f;
        xb[idx] = f2bf(v);
    } else if (idx < NPK_X + NPK_M1) {
        size_t j = idx - NPK_X;
        w1b[j] = f2bf(mlp1_w[j]);
    } else {
        size_t j = idx - NPK_X - NPK_M1;
        w2b[j] = f2bf(mlp2_w[j]);
    }
}

// ---------------- subject einsum via MFMA bf16 ----------------
// B-tile staged from f32 W_sub into padded LDS (r5); A-fragments now read from the
// swizzled xa layout -> one coalesced 1KB wave transaction each (was 16-row gather).
__global__ __launch_bounds__(256) void k_einsum(const unsigned short* __restrict__ xb,
                                                const float* __restrict__ W_sub,
                                                const int* __restrict__ sid,
                                                const float* __restrict__ b_sub,
                                                unsigned short* __restrict__ oute) {
    __shared__ unsigned short bt[32 * 520];   // 33.3 KB, +8 pad/row
    int t0 = blockIdx.x * 32, b = blockIdx.y;
    int s = sid[b];
    int tid = threadIdx.x, w = tid >> 6, lr = tid & 15, lg = (tid >> 4) & 3;
    {
        const float* src = W_sub + (size_t)s * (TT * TT);
        for (int i = tid; i < 2048; i += 256) {
            int row = i >> 6;
            int c0  = (i & 63) << 3;
            int rt  = t0 + row;
            union { unsigned short h[8]; uint4 q; } pk;
            if (rt < TT && c0 + 8 <= TT) {
                const float* p = src + (size_t)rt * TT + c0;
                float4 v0 = *(const float4*)p;
                float4 v1 = *(const float4*)(p + 4);
                pk.h[0] = f2bf(v0.x); pk.h[1] = f2bf(v0.y);
                pk.h[2] = f2bf(v0.z); pk.h[3] = f2bf(v0.w);
                pk.h[4] = f2bf(v1.x); pk.h[5] = f2bf(v1.y);
                pk.h[6] = f2bf(v1.z); pk.h[7] = f2bf(v1.w);
            } else {
                const float* p = src + (size_t)rt * TT;
                #pragma unroll
                for (int j = 0; j < 8; j++)
                    pk.h[j] = (rt < TT && c0 + j < TT) ? f2bf(p[c0 + j]) : (unsigned short)0;
            }
            *(uint4*)(&bt[row * 520 + c0]) = pk.q;
        }
    }
    __syncthreads();
    // A fragments: sp = w*2 (+1 for the upper 16 rows), lane-linear within tile
    const unsigned short* A0 = xb + ((size_t)(b * 8 + w * 2) * 16) * 512 + (size_t)(tid & 63) * 8;
    f32x4 acc[2][2] = {};
    for (int kk = 0; kk < 16; kk++) {
        BF8 a0, a1;
        a0.u = *(const u16x8*)(A0 + kk * 512);
        a1.u = *(const u16x8*)(A0 + 16 * 512 + kk * 512);
        #pragma unroll
        for (int nt = 0; nt < 2; nt++) {
            BF8 bf; bf.u = *(const u16x8*)(bt + (nt * 16 + lr) * 520 + kk * 32 + 8 * lg);
            acc[0][nt] = __builtin_amdgcn_mfma_f32_16x16x32_bf16(a0.b, bf.b, acc[0][nt], 0, 0, 0);
            acc[1][nt] = __builtin_amdgcn_mfma_f32_16x16x32_bf16(a1.b, bf.b, acc[1][nt], 0, 0, 0);
        }
    }
    const float* bg = b_sub + (size_t)s * TT;
    #pragma unroll
    for (int nt = 0; nt < 2; nt++) {
        int t = t0 + nt * 16 + lr;
        if (t < TT) {
            float bias = bg[t];
            #pragma unroll
            for (int mt = 0; mt < 2; mt++) {
                int crow = w * 32 + mt * 16 + 4 * lg;
                #pragma unroll
                for (int r = 0; r < 4; r++) {
                    int c = crow + r;
                    if (c < CC) oute[((size_t)b * CC + c) * TT + t] = f2bf(acc[mt][nt][r] + bias);
                }
            }
        }
    }
}

// ---------------- fused FIR+conv2, conv weights staged in LDS (r6 verbatim) ----------------
__global__ __launch_bounds__(384) void k_fc(const unsigned short* __restrict__ oute,
                                            const unsigned short* __restrict__ wcb,
                                            const float* __restrict__ b1f,
                                            const unsigned short* __restrict__ w2p,
                                            float* __restrict__ part) {
    __shared__ unsigned short e2[2][512];          // 2 KB
    __shared__ unsigned short pt[96][164];         // 31.5 KB
    __shared__ unsigned short aw[WID][168];        // 26.9 KB (160 + 8 pad)
    int chunk = blockIdx.x, b = blockIdx.y;
    int tid = threadIdx.x, w = tid >> 6, l = tid & 63, lr = l & 15, lg = l >> 4;
    BF8 af[5]; float4 bf4[5];
    #pragma unroll
    for (int ot = 0; ot < 5; ot++) {
        af[ot].u = *(const u16x8*)(wcb + (ot * 16 + lr) * 32 + 8 * lg);
        bf4[ot] = *(const float4*)(b1f + ot * 16 + 4 * lg);
    }
    f32x4 acc2[5] = {};
    for (int ci = 0; ci < 4; ci++) {
        int cp = chunk * 4 + ci;
        bool live = cp < 61;              // block-uniform
        __syncthreads();                  // prev-iter pt+aw reads done
        if (live) {
            if (tid < 250) {
                int cc = tid / 125, i = tid % 125;
                ((uint2*)e2[cc])[i] = ((const uint2*)(oute + ((size_t)b * CC + cp * 2 + cc) * TT))[i];
            }
            if (tid >= 232 && tid < 256) {   // zero-pad e[500..511] both rows
                int j = tid - 232; int cc = j / 12, i = 500 + (j % 12);
                e2[cc][i] = 0;
            }
            // stage this ci's conv-weight slab: 80 rows x 160 cols bf16, coalesced
            const unsigned short* wsrc = w2p + (size_t)cp * 160;
            for (int i = tid; i < WID * 20; i += 384) {
                int o = i / 20, c8 = i - o * 20;
                *(u16x8*)(&aw[o][c8 * 8]) = *(const u16x8*)(wsrc + (size_t)o * KP + c8 * 8);
            }
        }
        __syncthreads();                  // e2 + aw ready
        if (live) {
            #pragma unroll
            for (int cc = 0; cc < 2; cc++) {
                int t = w * 16 + lr;
                const unsigned short* ew = e2[cc] + 5 * t + 8 * lg;
                BF8 bfr;
                #pragma unroll
                for (int j = 0; j < 8; j++) bfr.u[j] = ew[j];
                f32x4 fa[5] = {};
                #pragma unroll
                for (int ot = 0; ot < 5; ot++)
                    fa[ot] = __builtin_amdgcn_mfma_f32_16x16x32_bf16(af[ot].b, bfr.b, fa[ot], 0, 0, 0);
                #pragma unroll
                for (int ot = 0; ot < 5; ot++) {
                    union { unsigned short s[4]; uint2 v; } pk;
                    #pragma unroll
                    for (int r = 0; r < 4; r++) pk.s[r] = f2bf(eluf(fa[ot][r] + bf4[ot][r]));
                    *(uint2*)&pt[t][cc * 80 + ot * 16 + 4 * lg] = pk.v;
                }
            }
        }
        __syncthreads();                  // pt ready
        if (live) {
            #pragma unroll
            for (int kl = 0; kl < 5; kl++) {
                BF8 bf; bf.u = *(const u16x8*)(&pt[w * 16 + lr][kl * 32 + lg * 8]);
                #pragma unroll
                for (int mt = 0; mt < 5; mt++) {
                    BF8 a; a.u = *(const u16x8*)(&aw[mt * 16 + lr][kl * 32 + lg * 8]);
                    acc2[mt] = __builtin_amdgcn_mfma_f32_16x16x32_bf16(a.b, bf.b, acc2[mt], 0, 0, 0);
                }
            }
        }
    }
    float* pp = part + ((size_t)(chunk * BB + b) * WID) * TP;
    int t = w * 16 + lr;
    #pragma unroll
    for (int mt = 0; mt < 5; mt++) {
        int ob = mt * 16 + 4 * lg;
        #pragma unroll
        for (int r = 0; r < 4; r++)
            pp[(size_t)(ob + r) * TP + t] = acc2[mt][r];
    }
}

// ---------------- reduce split-K + bn2 + elu + proj -> z_bf (r3 verbatim) ----------
__global__ __launch_bounds__(256) void k_redproj(const float* __restrict__ part,
                                                 const float* __restrict__ scale2,
                                                 const float* __restrict__ shift2f,
                                                 const float* __restrict__ pw,
                                                 const float* __restrict__ pb,
                                                 unsigned short* __restrict__ zbf) {
    __shared__ float ly[WID * 12];   // 960
    __shared__ float lw[EMB * WID];  // 640
    int tq = blockIdx.x, b = blockIdx.y;
    int tid = threadIdx.x;
    int t0 = tq * 12;
    for (int i = tid; i < EMB * WID; i += 256) lw[i] = pw[i];
    if (tid < 240) {                 // 80 o x 3 float4
        int o = tid / 3, q = tid % 3;
        const float* pbase = part + (size_t)b * (WID * TP) + o * TP + t0 + 4 * q;
        float4 a = {0.f, 0.f, 0.f, 0.f};
        #pragma unroll
        for (int ks = 0; ks < KSPLIT; ks++) {
            float4 v = *(const float4*)(pbase + (size_t)ks * (BB * WID * TP));
            a.x += v.x; a.y += v.y; a.z += v.z; a.w += v.w;
        }
        float sc = scale2[o], sh = shift2f[o];
        ly[o * 12 + 4 * q + 0] = eluf(a.x * sc + sh);
        ly[o * 12 + 4 * q + 1] = eluf(a.y * sc + sh);
        ly[o * 12 + 4 * q + 2] = eluf(a.z * sc + sh);
        ly[o * 12 + 4 * q + 3] = eluf(a.w * sc + sh);
    }
    __syncthreads();
    if (tid < 12 * EMB) {
        int e = tid & 7, tl = tid >> 3;
        float acc = pb[e];
        #pragma unroll 10
        for (int o = 0; o < WID; o++) acc = fmaf(ly[o * 12 + tl], lw[e * WID + o], acc);
        zbf[(size_t)b * HID + (t0 + tl) * EMB + e] = f2bf(acc);
    }
}

// ---------------- mlp1: 128 blocks (64 col-units x 2 row-halves); 4-wave K-split ----
__global__ __launch_bounds__(256) void k_mlp1(const unsigned short* __restrict__ zbf,
                                              const unsigned short* __restrict__ w1b,
                                              const float* __restrict__ bias,
                                              float* __restrict__ z1,
                                              unsigned short* __restrict__ gbf) {
    __shared__ float accb[4][64][4];
    int cu = blockIdx.x >> 1, rh = blockIdx.x & 1;
    int tid = threadIdx.x, w = tid >> 6, l = tid & 63, lr = l & 15, lg = l >> 4;
    int pcol = cu * 16 + lr;
    const unsigned short* wr = w1b + (size_t)pcol * HID + w * 192 + 8 * lg;
    const unsigned short* za = zbf + (size_t)(rh * 16 + lr) * HID + w * 192 + 8 * lg;
    f32x4 acc = {};
    #pragma unroll
    for (int kb = 0; kb < 192; kb += 32) {
        BF8 bf; bf.u = *(const u16x8*)(wr + kb);
        BF8 a;  a.u  = *(const u16x8*)(za + kb);
        acc = __builtin_amdgcn_mfma_f32_16x16x32_bf16(a.b, bf.b, acc, 0, 0, 0);
    }
    #pragma unroll
    for (int r = 0; r < 4; r++) accb[w][l][r] = acc[r];
    __syncthreads();
    if (w == 0) {
        float bs = bias[pcol];
        #pragma unroll
        for (int r = 0; r < 4; r++) {
            int row = rh * 16 + 4 * lg + r;
            float v = bs;
            #pragma unroll
            for (int q = 0; q < 4; q++) v += accb[q][l][r];
            z1[(size_t)row * PROJ + pcol] = v;
            gbf[(size_t)row * PROJ + pcol] = f2bf(0.5f * v * (1.f + erff(v * 0.70710678118654752f)));
        }
    }
}

// ---------------- mlp2: 128 blocks; y = z1 + Gbf @ W2b^T + b2; 4-wave K-split ----
__global__ __launch_bounds__(256) void k_mlp2(const unsigned short* __restrict__ gbf,
                                              const float* __restrict__ z1,
                                              const unsigned short* __restrict__ w2b,
                                              const float* __restrict__ bias,
                                              float* __restrict__ y) {
    __shared__ float accb[4][64][4];
    int cu = blockIdx.x >> 1, rh = blockIdx.x & 1;
    int tid = threadIdx.x, w = tid >> 6, l = tid & 63, lr = l & 15, lg = l >> 4;
    int pc = cu * 16 + lr;
    const unsigned short* wr = w2b + (size_t)pc * PROJ + w * 256 + 8 * lg;
    const unsigned short* ga = gbf + (size_t)(rh * 16 + lr) * PROJ + w * 256 + 8 * lg;
    f32x4 acc = {};
    #pragma unroll
    for (int kb = 0; kb < 256; kb += 32) {
        BF8 bf; bf.u = *(const u16x8*)(wr + kb);
        BF8 a;  a.u  = *(const u16x8*)(ga + kb);
        acc = __builtin_amdgcn_mfma_f32_16x16x32_bf16(a.b, bf.b, acc, 0, 0, 0);
    }
    #pragma unroll
    for (int r = 0; r < 4; r++) accb[w][l][r] = acc[r];
    __syncthreads();
    if (w == 0) {
        float bs = bias[pc];
        #pragma unroll
        for (int r = 0; r < 4; r++) {
            int row = rh * 16 + 4 * lg + r;
            float v = bs + z1[(size_t)row * PROJ + pc];
            #pragma unroll
            for (int q = 0; q < 4; q++) v += accb[q][l][r];
            y[(size_t)row * PROJ + pc] = v;
        }
    }
}

// ---------------- LayerNorm over 1024 per row -> d_out (r0 verbatim) ----------------
__global__ __launch_bounds__(256) void k_ln(const float* __restrict__ y,
                                            const float* __restrict__ lg,
                                            const float* __restrict__ lb,
                                            float* __restrict__ out) {
    int b = blockIdx.x, tid = threadIdx.x;
    const float4* yr = (const float4*)(y + (size_t)b * PROJ);
    float4 v = yr[tid];
    float s  = v.x + v.y + v.z + v.w;
    float sq = v.x*v.x + v.y*v.y + v.z*v.z + v.w*v.w;
    #pragma unroll
    for (int off = 32; off > 0; off >>= 1) {
        s  += __shfl_down(s, off);
        sq += __shfl_down(sq, off);
    }
    __shared__ float ss[4], ssq[4];
    int wv = tid >> 6, lane = tid & 63;
    if (lane == 0) { ss[wv] = s; ssq[wv] = sq; }
    __syncthreads();
    __shared__ float smu, sinv;
    if (tid == 0) {
        float Sm = ss[0] + ss[1] + ss[2] + ss[3];
        float Sq = ssq[0] + ssq[1] + ssq[2] + ssq[3];
        float mu = Sm * (1.f / PROJ);
        float var = Sq * (1.f / PROJ) - mu * mu;
        smu = mu;
        sinv = rsqrtf(var + EPSF);
    }
    __syncthreads();
    float mu = smu, inv = sinv;
    float4 g4 = ((const float4*)lg)[tid];
    float4 b4 = ((const float4*)lb)[tid];
    float4 o4;
    o4.x = (v.x - mu) * inv * g4.x + b4.x;
    o4.y = (v.y - mu) * inv * g4.y + b4.y;
    o4.z = (v.z - mu) * inv * g4.z + b4.z;
    o4.w = (v.w - mu) * inv * g4.w + b4.w;
    ((float4*)(out + (size_t)b * PROJ))[tid] = o4;
}

extern "C" void kernel_launch(void* const* d_in, const int* in_sizes, int n_in,
                              void* d_out, int out_size, void* d_ws, size_t ws_size,
                              hipStream_t stream) {
    const float* x        = (const float*)d_in[0];
    const int*   sid      = (const int*)  d_in[1];
    const float* W_sub    = (const float*)d_in[2];
    const float* b_sub    = (const float*)d_in[3];
    const float* conv1_w  = (const float*)d_in[4];
    const float* conv1_b  = (const float*)d_in[5];
    const float* bn1_g    = (const float*)d_in[6];
    const float* bn1_b    = (const float*)d_in[7];
    const float* bn1_m    = (const float*)d_in[8];
    const float* bn1_v    = (const float*)d_in[9];
    const float* conv2_w  = (const float*)d_in[10];
    const float* conv2_b  = (const float*)d_in[11];
    const float* bn2_g    = (const float*)d_in[12];
    const float* bn2_b    = (const float*)d_in[13];
    const float* bn2_m    = (const float*)d_in[14];
    const float* bn2_v    = (const float*)d_in[15];
    const float* proj_w   = (const float*)d_in[16];
    const float* proj_b   = (const float*)d_in[17];
    const float* mlp1_w   = (const float*)d_in[18];
    const float* mlp1_b   = (const float*)d_in[19];
    const float* mlp2_w   = (const float*)d_in[20];
    const float* mlp2_b   = (const float*)d_in[21];
    const float* ln_g     = (const float*)d_in[22];
    const float* ln_b     = (const float*)d_in[23];
    float* out = (float*)d_out;
    float* ws  = (float*)d_ws;

    unsigned short* ws_e   = (unsigned short*)(ws + OFF_E);
    unsigned short* ws_xb  = (unsigned short*)(ws + OFF_XB);
    unsigned short* ws_w2p = (unsigned short*)(ws + OFF_W2P);
    float* ws_part = ws + OFF_PART;
    unsigned short* ws_zbf = (unsigned short*)(ws + OFF_Z);
    float* ws_z1   = ws + OFF_Z1;
    unsigned short* ws_gbf = (unsigned short*)(ws + OFF_G);
    float* ws_y    = ws + OFF_Y;
    unsigned short* ws_w1b = (unsigned short*)(ws + OFF_W1B);
    unsigned short* ws_w2b = (unsigned short*)(ws + OFF_W2B);
    unsigned short* ws_wcb = (unsigned short*)(ws + OFF_WCB);
    float* ws_b1f  = ws + OFF_B1F;
    float* ws_sc2  = ws + OFF_SC2;
    float* ws_sh2  = ws + OFF_SH2;

    hipLaunchKernelGGL(k_pack, dim3(WID + (NPK_LIN + 255) / 256), dim3(256), 0, stream,
                       x, conv2_w, mlp1_w, mlp2_w,
                       conv1_w, conv1_b, bn1_g, bn1_b, bn1_m, bn1_v,
                       conv2_b, bn2_g, bn2_b, bn2_m, bn2_v,
                       ws_xb, ws_w2p, ws_w1b, ws_w2b,
                       ws_wcb, ws_b1f, ws_sc2, ws_sh2);

    hipLaunchKernelGGL(k_einsum, dim3(16, BB), dim3(256), 0, stream,
                       ws_xb, W_sub, sid, b_sub, ws_e);

    hipLaunchKernelGGL(k_fc, dim3(KSPLIT, BB), dim3(384), 0, stream,
                       ws_e, ws_wcb, ws_b1f, ws_w2p, ws_part);

    hipLaunchKernelGGL(k_redproj, dim3(8, BB), dim3(256), 0, stream,
                       ws_part, ws_sc2, ws_sh2, proj_w, proj_b, ws_zbf);

    hipLaunchKernelGGL(k_mlp1, dim3(128), dim3(256), 0, stream,
                       ws_zbf, ws_w1b, mlp1_b, ws_z1, ws_gbf);

    hipLaunchKernelGGL(k_mlp2, dim3(128), dim3(256), 0, stream,
                       ws_gbf, ws_z1, ws_w2b, mlp2_b, ws_y);

    hipLaunchKernelGGL(k_ln, dim3(BB), dim3(256), 0, stream,
                       ws_y, ln_g, ln_b, out);
}

// Round 8
// 188.695 us; speedup vs baseline: 1.3189x; 1.0227x over previous
//
#include <hip/hip_runtime.h>
#include <math.h>

// Problem constants
#define BB 32
#define CC 122
#define TT 500
#define SS 13
#define WID 80
#define EMB 8
#define PROJ 1024
#define HID 768
#define TP 96          // pooled time length
#define EPSF 1e-5f
#define KP 9760        // conv2 flat K' = 122*80
#define KSPLIT 16      // 16 chunks x 4 c-pairs (c-pairs 61..63 are zero/skip)

typedef float f32x4 __attribute__((ext_vector_type(4)));
typedef __bf16 bf16x8 __attribute__((ext_vector_type(8)));
typedef unsigned short u16x8 __attribute__((ext_vector_type(8)));
union BF8 { u16x8 u; bf16x8 b; };

// float -> bf16 bits, round-to-nearest-even
__device__ __forceinline__ unsigned short f2bf(float f) {
    union { float f; unsigned u; } v; v.f = f;
    unsigned r = v.u + 0x7FFFu + ((v.u >> 16) & 1u);
    return (unsigned short)(r >> 16);
}

__device__ __forceinline__ float eluf(float x) {
    return x > 0.f ? x : __expf(x) - 1.f;
}

// ---------------- workspace layout (float offsets) ----------------
#define OFF_E    ((size_t)0)            // oute (B,C,T) bf16
#define OFF_XB   ((size_t)1952000)      // xa swizzled A-fragments (B,8,16,64,8) bf16
#define OFF_W2P  ((size_t)4704512)      // w2p (80,9760) bf16
#define OFF_PART ((size_t)20086272)     // (KSPLIT,B,WID,TP) f32
#define OFF_Z    ((size_t)24018432)     // z_bf (B,HID) bf16
#define OFF_Z1   ((size_t)24030720)     // z1 (B,PROJ) f32
#define OFF_G    ((size_t)24063488)     // g_bf (B,PROJ) bf16
#define OFF_Y    ((size_t)24079872)     // y (B,PROJ) f32
#define OFF_W1B  ((size_t)24112640)     // w1b (PROJ,HID) bf16
#define OFF_W2B  ((size_t)24505856)     // w2b (PROJ,PROJ) bf16
#define OFF_WCB  ((size_t)25030144)     // wcb (80,32) bf16
#define OFF_B1F  ((size_t)25031424)     // (WID)
#define OFF_SC2  ((size_t)25031504)     // (WID)
#define OFF_SH2  ((size_t)25031584)     // (WID)

#define NPK_X  (2097152)   // 32*8*16*64*8  (swizzled A-fragment layout)
#define NPK_M1 (786432)    // 1024*768
#define NPK_M2 (1048576)   // 1024*1024
#define M1M2_CHUNKS ((NPK_M1 + NPK_M2) / 8)   // 229376 8-elem chunks
#define NCPY 256           // einsum backfill blocks for m1/m2 pack
#define NEIN (512 + NCPY + WID)   // einsum grid: 512 compute + 256 copy + 80 transpose

// ---------------- pack: xb swizzle staging + prep constants (block 0) ----------------
// xa layout: [b][sp][kk][lane][8] -- tile (sp,kk) is the exact 16x32 MFMA A-fragment
// in lane order (lane = lg*16+lr; element (row = sp*16+lr, col = kk*32 + lg*8 + u)).
// w1b/w2b/w2p staging moved into k_einsum's backfill blocks (runs in einsum's
// drain shadow; nothing needs them until dispatches #3/#5/#6).
__global__ __launch_bounds__(256) void k_pack(const float* __restrict__ x,
                                              const float* __restrict__ conv1_w, const float* __restrict__ conv1_b,
                                              const float* __restrict__ g1, const float* __restrict__ b1,
                                              const float* __restrict__ m1, const float* __restrict__ v1,
                                              const float* __restrict__ conv2_b, const float* __restrict__ g2,
                                              const float* __restrict__ b2, const float* __restrict__ m2,
                                              const float* __restrict__ v2,
                                              unsigned short* __restrict__ xb,
                                              unsigned short* __restrict__ wcb, float* __restrict__ bias1f,
                                              float* __restrict__ scale2, float* __restrict__ shift2f) {
    if (blockIdx.x == 0) {
        int o = threadIdx.x;
        if (o < WID) {
            float s1 = g1[o] * rsqrtf(v1[o] + EPSF);
            float sh1 = b1[o] - m1[o] * s1;
            #pragma unroll
            for (int d = 0; d < 21; d++) {
                int klo = d - 16; if (klo < 0) klo = 0;
                int khi = d;      if (khi > 4) khi = 4;
                float acc = 0.f;
                for (int k = klo; k <= khi; k++) acc += conv1_w[o*5 + k];
                wcb[o*32 + d] = f2bf(acc * s1 * (1.f/17.f));
            }
            #pragma unroll
            for (int d = 21; d < 32; d++) wcb[o*32 + d] = 0;
            bias1f[o] = conv1_b[o] * s1 + sh1;
            float s2 = g2[o] * rsqrtf(v2[o] + EPSF);
            scale2[o] = s2;
            shift2f[o] = conv2_b[o] * s2 + (b2[o] - m2[o] * s2);
        }
    }
    size_t idx = (size_t)blockIdx.x * 256 + threadIdx.x;
    if (idx >= (size_t)NPK_X) return;
    // decode swizzled position: idx = (((b*8+sp)*16+kk)*64 + l)*8 + u
    int u = (int)(idx & 7);
    size_t j = idx >> 3;
    int l  = (int)(j & 63); j >>= 6;
    int kk = (int)(j & 15); j >>= 4;
    int sp = (int)(j & 7);
    int b  = (int)(j >> 3);
    int c  = sp * 16 + (l & 15);
    int s  = kk * 32 + (l >> 4) * 8 + u;
    float v = (c < CC && s < TT) ? x[((size_t)b * CC + c) * TT + s] : 0.f;
    xb[idx] = f2bf(v);
}

// ---------------- subject einsum via MFMA bf16 + backfill weight staging ----------------
// Blocks 0..511: compute (B-tile from f32 W_sub in padded LDS, swizzled A loads).
// Blocks 512..767: m1/m2 bf16 pack (grid-stride, float4). Blocks 768..847: w2p
// LDS-transpose (one o each, aliasing bt's LDS). Backfill runs while compute
// blocks drain -- machine time that was previously idle.
__global__ __launch_bounds__(256) void k_einsum(const unsigned short* __restrict__ xb,
                                                const float* __restrict__ W_sub,
                                                const int* __restrict__ sid,
                                                const float* __restrict__ b_sub,
                                                const float* __restrict__ mlp1_w,
                                                const float* __restrict__ mlp2_w,
                                                const float* __restrict__ conv2_w,
                                                unsigned short* __restrict__ oute,
                                                unsigned short* __restrict__ w1b,
                                                unsigned short* __restrict__ w2b,
                                                unsigned short* __restrict__ w2p) {
    __shared__ unsigned short bt[32 * 520];   // 33.3 KB, +8 pad/row
    int bid = blockIdx.x, tid = threadIdx.x;
    if (bid >= 512) {
        int cid = bid - 512;
        if (cid < NCPY) {
            // m1/m2 bf16 pack, 8 elements per step
            for (unsigned jj = (unsigned)cid * 256 + tid; jj < (unsigned)M1M2_CHUNKS; jj += NCPY * 256) {
                unsigned e0 = jj * 8;
                const float* src;
                unsigned short* dst;
                if (e0 < (unsigned)NPK_M1) { src = mlp1_w + e0; dst = w1b + e0; }
                else { src = mlp2_w + (e0 - NPK_M1); dst = w2b + (e0 - NPK_M1); }
                float4 v0 = *(const float4*)src;
                float4 v1 = *(const float4*)(src + 4);
                union { unsigned short h[8]; uint4 q; } pk;
                pk.h[0] = f2bf(v0.x); pk.h[1] = f2bf(v0.y);
                pk.h[2] = f2bf(v0.z); pk.h[3] = f2bf(v0.w);
                pk.h[4] = f2bf(v1.x); pk.h[5] = f2bf(v1.y);
                pk.h[6] = f2bf(v1.z); pk.h[7] = f2bf(v1.w);
                *(uint4*)dst = pk.q;
            }
        } else {
            // w2p transpose for one output unit o (alias bt's LDS as [80][124])
            unsigned short (*lt)[124] = (unsigned short (*)[124])bt;
            int o = cid - NCPY;
            const float* src = conv2_w + (size_t)o * (WID * CC);
            for (int i = tid; i < WID * CC; i += 256) {
                int op = i / CC, c = i - op * CC;
                lt[op][c] = f2bf(src[i]);
            }
            __syncthreads();
            unsigned short* dst = w2p + (size_t)o * KP;
            for (int jj = tid; jj < KP / 8; jj += 256) {
                int k0 = jj * 8;
                union { unsigned short h[8]; uint4 q; } pk;
                #pragma unroll
                for (int u = 0; u < 8; u++) {
                    int k = k0 + u;
                    pk.h[u] = lt[k % WID][k / WID];
                }
                *(uint4*)(dst + k0) = pk.q;
            }
        }
        return;
    }
    int t0 = (bid & 15) * 32, b = bid >> 4;
    int s = sid[b];
    int w = tid >> 6, lr = tid & 15, lg = (tid >> 4) & 3;
    {
        const float* src = W_sub + (size_t)s * (TT * TT);
        for (int i = tid; i < 2048; i += 256) {
            int row = i >> 6;
            int c0  = (i & 63) << 3;
            int rt  = t0 + row;
            union { unsigned short h[8]; uint4 q; } pk;
            if (rt < TT && c0 + 8 <= TT) {
                const float* p = src + (size_t)rt * TT + c0;
                float4 v0 = *(const float4*)p;
                float4 v1 = *(const float4*)(p + 4);
                pk.h[0] = f2bf(v0.x); pk.h[1] = f2bf(v0.y);
                pk.h[2] = f2bf(v0.z); pk.h[3] = f2bf(v0.w);
                pk.h[4] = f2bf(v1.x); pk.h[5] = f2bf(v1.y);
                pk.h[6] = f2bf(v1.z); pk.h[7] = f2bf(v1.w);
            } else {
                const float* p = src + (size_t)rt * TT;
                #pragma unroll
                for (int jj = 0; jj < 8; jj++)
                    pk.h[jj] = (rt < TT && c0 + jj < TT) ? f2bf(p[c0 + jj]) : (unsigned short)0;
            }
            *(uint4*)(&bt[row * 520 + c0]) = pk.q;
        }
    }
    __syncthreads();
    // A fragments: sp = w*2 (+1 for upper 16 rows), lane-linear within tile
    const unsigned short* A0 = xb + ((size_t)(b * 8 + w * 2) * 16) * 512 + (size_t)(tid & 63) * 8;
    f32x4 acc[2][2] = {};
    for (int kk = 0; kk < 16; kk++) {
        BF8 a0, a1;
        a0.u = *(const u16x8*)(A0 + kk * 512);
        a1.u = *(const u16x8*)(A0 + 16 * 512 + kk * 512);
        #pragma unroll
        for (int nt = 0; nt < 2; nt++) {
            BF8 bf; bf.u = *(const u16x8*)(bt + (nt * 16 + lr) * 520 + kk * 32 + 8 * lg);
            acc[0][nt] = __builtin_amdgcn_mfma_f32_16x16x32_bf16(a0.b, bf.b, acc[0][nt], 0, 0, 0);
            acc[1][nt] = __builtin_amdgcn_mfma_f32_16x16x32_bf16(a1.b, bf.b, acc[1][nt], 0, 0, 0);
        }
    }
    const float* bg = b_sub + (size_t)s * TT;
    #pragma unroll
    for (int nt = 0; nt < 2; nt++) {
        int t = t0 + nt * 16 + lr;
        if (t < TT) {
            float bias = bg[t];
            #pragma unroll
            for (int mt = 0; mt < 2; mt++) {
                int crow = w * 32 + mt * 16 + 4 * lg;
                #pragma unroll
                for (int r = 0; r < 4; r++) {
                    int c = crow + r;
                    if (c < CC) oute[((size_t)b * CC + c) * TT + t] = f2bf(acc[mt][nt][r] + bias);
                }
            }
        }
    }
}

// ---------------- fused FIR+conv2, conv weights staged in LDS (r6 verbatim) ----------------
__global__ __launch_bounds__(384) void k_fc(const unsigned short* __restrict__ oute,
                                            const unsigned short* __restrict__ wcb,
                                            const float* __restrict__ b1f,
                                            const unsigned short* __restrict__ w2p,
                                            float* __restrict__ part) {
    __shared__ unsigned short e2[2][512];          // 2 KB
    __shared__ unsigned short pt[96][164];         // 31.5 KB
    __shared__ unsigned short aw[WID][168];        // 26.9 KB (160 + 8 pad)
    int chunk = blockIdx.x, b = blockIdx.y;
    int tid = threadIdx.x, w = tid >> 6, l = tid & 63, lr = l & 15, lg = l >> 4;
    BF8 af[5]; float4 bf4[5];
    #pragma unroll
    for (int ot = 0; ot < 5; ot++) {
        af[ot].u = *(const u16x8*)(wcb + (ot * 16 + lr) * 32 + 8 * lg);
        bf4[ot] = *(const float4*)(b1f + ot * 16 + 4 * lg);
    }
    f32x4 acc2[5] = {};
    for (int ci = 0; ci < 4; ci++) {
        int cp = chunk * 4 + ci;
        bool live = cp < 61;              // block-uniform
        __syncthreads();                  // prev-iter pt+aw reads done
        if (live) {
            if (tid < 250) {
                int cc = tid / 125, i = tid % 125;
                ((uint2*)e2[cc])[i] = ((const uint2*)(oute + ((size_t)b * CC + cp * 2 + cc) * TT))[i];
            }
            if (tid >= 232 && tid < 256) {   // zero-pad e[500..511] both rows
                int j = tid - 232; int cc = j / 12, i = 500 + (j % 12);
                e2[cc][i] = 0;
            }
            // stage this ci's conv-weight slab: 80 rows x 160 cols bf16, coalesced
            const unsigned short* wsrc = w2p + (size_t)cp * 160;
            for (int i = tid; i < WID * 20; i += 384) {
                int o = i / 20, c8 = i - o * 20;
                *(u16x8*)(&aw[o][c8 * 8]) = *(const u16x8*)(wsrc + (size_t)o * KP + c8 * 8);
            }
        }
        __syncthreads();                  // e2 + aw ready
        if (live) {
            #pragma unroll
            for (int cc = 0; cc < 2; cc++) {
                int t = w * 16 + lr;
                const unsigned short* ew = e2[cc] + 5 * t + 8 * lg;
                BF8 bfr;
                #pragma unroll
                for (int j = 0; j < 8; j++) bfr.u[j] = ew[j];
                f32x4 fa[5] = {};
                #pragma unroll
                for (int ot = 0; ot < 5; ot++)
                    fa[ot] = __builtin_amdgcn_mfma_f32_16x16x32_bf16(af[ot].b, bfr.b, fa[ot], 0, 0, 0);
                #pragma unroll
                for (int ot = 0; ot < 5; ot++) {
                    union { unsigned short s[4]; uint2 v; } pk;
                    #pragma unroll
                    for (int r = 0; r < 4; r++) pk.s[r] = f2bf(eluf(fa[ot][r] + bf4[ot][r]));
                    *(uint2*)&pt[t][cc * 80 + ot * 16 + 4 * lg] = pk.v;
                }
            }
        }
        __syncthreads();                  // pt ready
        if (live) {
            #pragma unroll
            for (int kl = 0; kl < 5; kl++) {
                BF8 bf; bf.u = *(const u16x8*)(&pt[w * 16 + lr][kl * 32 + lg * 8]);
                #pragma unroll
                for (int mt = 0; mt < 5; mt++) {
                    BF8 a; a.u = *(const u16x8*)(&aw[mt * 16 + lr][kl * 32 + lg * 8]);
                    acc2[mt] = __builtin_amdgcn_mfma_f32_16x16x32_bf16(a.b, bf.b, acc2[mt], 0, 0, 0);
                }
            }
        }
    }
    float* pp = part + ((size_t)(chunk * BB + b) * WID) * TP;
    int t = w * 16 + lr;
    #pragma unroll
    for (int mt = 0; mt < 5; mt++) {
        int ob = mt * 16 + 4 * lg;
        #pragma unroll
        for (int r = 0; r < 4; r++)
            pp[(size_t)(ob + r) * TP + t] = acc2[mt][r];
    }
}

// ---------------- reduce split-K + bn2 + elu + proj -> z_bf (r3 verbatim) ----------
__global__ __launch_bounds__(256) void k_redproj(const float* __restrict__ part,
                                                 const float* __restrict__ scale2,
                                                 const float* __restrict__ shift2f,
                                                 const float* __restrict__ pw,
                                                 const float* __restrict__ pb,
                                                 unsigned short* __restrict__ zbf) {
    __shared__ float ly[WID * 12];   // 960
    __shared__ float lw[EMB * WID];  // 640
    int tq = blockIdx.x, b = blockIdx.y;
    int tid = threadIdx.x;
    int t0 = tq * 12;
    for (int i = tid; i < EMB * WID; i += 256) lw[i] = pw[i];
    if (tid < 240) {                 // 80 o x 3 float4
        int o = tid / 3, q = tid % 3;
        const float* pbase = part + (size_t)b * (WID * TP) + o * TP + t0 + 4 * q;
        float4 a = {0.f, 0.f, 0.f, 0.f};
        #pragma unroll
        for (int ks = 0; ks < KSPLIT; ks++) {
            float4 v = *(const float4*)(pbase + (size_t)ks * (BB * WID * TP));
            a.x += v.x; a.y += v.y; a.z += v.z; a.w += v.w;
        }
        float sc = scale2[o], sh = shift2f[o];
        ly[o * 12 + 4 * q + 0] = eluf(a.x * sc + sh);
        ly[o * 12 + 4 * q + 1] = eluf(a.y * sc + sh);
        ly[o * 12 + 4 * q + 2] = eluf(a.z * sc + sh);
        ly[o * 12 + 4 * q + 3] = eluf(a.w * sc + sh);
    }
    __syncthreads();
    if (tid < 12 * EMB) {
        int e = tid & 7, tl = tid >> 3;
        float acc = pb[e];
        #pragma unroll 10
        for (int o = 0; o < WID; o++) acc = fmaf(ly[o * 12 + tl], lw[e * WID + o], acc);
        zbf[(size_t)b * HID + (t0 + tl) * EMB + e] = f2bf(acc);
    }
}

// ---------------- mlp1: 128 blocks (64 col-units x 2 row-halves); 4-wave K-split ----
__global__ __launch_bounds__(256) void k_mlp1(const unsigned short* __restrict__ zbf,
                                              const unsigned short* __restrict__ w1b,
                                              const float* __restrict__ bias,
                                              float* __restrict__ z1,
                                              unsigned short* __restrict__ gbf) {
    __shared__ float accb[4][64][4];
    int cu = blockIdx.x >> 1, rh = blockIdx.x & 1;
    int tid = threadIdx.x, w = tid >> 6, l = tid & 63, lr = l & 15, lg = l >> 4;
    int pcol = cu * 16 + lr;
    const unsigned short* wr = w1b + (size_t)pcol * HID + w * 192 + 8 * lg;
    const unsigned short* za = zbf + (size_t)(rh * 16 + lr) * HID + w * 192 + 8 * lg;
    f32x4 acc = {};
    #pragma unroll
    for (int kb = 0; kb < 192; kb += 32) {
        BF8 bf; bf.u = *(const u16x8*)(wr + kb);
        BF8 a;  a.u  = *(const u16x8*)(za + kb);
        acc = __builtin_amdgcn_mfma_f32_16x16x32_bf16(a.b, bf.b, acc, 0, 0, 0);
    }
    #pragma unroll
    for (int r = 0; r < 4; r++) accb[w][l][r] = acc[r];
    __syncthreads();
    if (w == 0) {
        float bs = bias[pcol];
        #pragma unroll
        for (int r = 0; r < 4; r++) {
            int row = rh * 16 + 4 * lg + r;
            float v = bs;
            #pragma unroll
            for (int q = 0; q < 4; q++) v += accb[q][l][r];
            z1[(size_t)row * PROJ + pcol] = v;
            gbf[(size_t)row * PROJ + pcol] = f2bf(0.5f * v * (1.f + erff(v * 0.70710678118654752f)));
        }
    }
}

// ---------------- mlp2: 128 blocks; y = z1 + Gbf @ W2b^T + b2; 4-wave K-split ----
__global__ __launch_bounds__(256) void k_mlp2(const unsigned short* __restrict__ gbf,
                                              const float* __restrict__ z1,
                                              const unsigned short* __restrict__ w2b,
                                              const float* __restrict__ bias,
                                              float* __restrict__ y) {
    __shared__ float accb[4][64][4];
    int cu = blockIdx.x >> 1, rh = blockIdx.x & 1;
    int tid = threadIdx.x, w = tid >> 6, l = tid & 63, lr = l & 15, lg = l >> 4;
    int pc = cu * 16 + lr;
    const unsigned short* wr = w2b + (size_t)pc * PROJ + w * 256 + 8 * lg;
    const unsigned short* ga = gbf + (size_t)(rh * 16 + lr) * PROJ + w * 256 + 8 * lg;
    f32x4 acc = {};
    #pragma unroll
    for (int kb = 0; kb < 256; kb += 32) {
        BF8 bf; bf.u = *(const u16x8*)(wr + kb);
        BF8 a;  a.u  = *(const u16x8*)(ga + kb);
        acc = __builtin_amdgcn_mfma_f32_16x16x32_bf16(a.b, bf.b, acc, 0, 0, 0);
    }
    #pragma unroll
    for (int r = 0; r < 4; r++) accb[w][l][r] = acc[r];
    __syncthreads();
    if (w == 0) {
        float bs = bias[pc];
        #pragma unroll
        for (int r = 0; r < 4; r++) {
            int row = rh * 16 + 4 * lg + r;
            float v = bs + z1[(size_t)row * PROJ + pc];
            #pragma unroll
            for (int q = 0; q < 4; q++) v += accb[q][l][r];
            y[(size_t)row * PROJ + pc] = v;
        }
    }
}

// ---------------- LayerNorm over 1024 per row -> d_out (r0 verbatim) ----------------
__global__ __launch_bounds__(256) void k_ln(const float* __restrict__ y,
                                            const float* __restrict__ lg,
                                            const float* __restrict__ lb,
                                            float* __restrict__ out) {
    int b = blockIdx.x, tid = threadIdx.x;
    const float4* yr = (const float4*)(y + (size_t)b * PROJ);
    float4 v = yr[tid];
    float s  = v.x + v.y + v.z + v.w;
    float sq = v.x*v.x + v.y*v.y + v.z*v.z + v.w*v.w;
    #pragma unroll
    for (int off = 32; off > 0; off >>= 1) {
        s  += __shfl_down(s, off);
        sq += __shfl_down(sq, off);
    }
    __shared__ float ss[4], ssq[4];
    int wv = tid >> 6, lane = tid & 63;
    if (lane == 0) { ss[wv] = s; ssq[wv] = sq; }
    __syncthreads();
    __shared__ float smu, sinv;
    if (tid == 0) {
        float Sm = ss[0] + ss[1] + ss[2] + ss[3];
        float Sq = ssq[0] + ssq[1] + ssq[2] + ssq[3];
        float mu = Sm * (1.f / PROJ);
        float var = Sq * (1.f / PROJ) - mu * mu;
        smu = mu;
        sinv = rsqrtf(var + EPSF);
    }
    __syncthreads();
    float mu = smu, inv = sinv;
    float4 g4 = ((const float4*)lg)[tid];
    float4 b4 = ((const float4*)lb)[tid];
    float4 o4;
    o4.x = (v.x - mu) * inv * g4.x + b4.x;
    o4.y = (v.y - mu) * inv * g4.y + b4.y;
    o4.z = (v.z - mu) * inv * g4.z + b4.z;
    o4.w = (v.w - mu) * inv * g4.w + b4.w;
    ((float4*)(out + (size_t)b * PROJ))[tid] = o4;
}

extern "C" void kernel_launch(void* const* d_in, const int* in_sizes, int n_in,
                              void* d_out, int out_size, void* d_ws, size_t ws_size,
                              hipStream_t stream) {
    const float* x        = (const float*)d_in[0];
    const int*   sid      = (const int*)  d_in[1];
    const float* W_sub    = (const float*)d_in[2];
    const float* b_sub    = (const float*)d_in[3];
    const float* conv1_w  = (const float*)d_in[4];
    const float* conv1_b  = (const float*)d_in[5];
    const float* bn1_g    = (const float*)d_in[6];
    const float* bn1_b    = (const float*)d_in[7];
    const float* bn1_m    = (const float*)d_in[8];
    const float* bn1_v    = (const float*)d_in[9];
    const float* conv2_w  = (const float*)d_in[10];
    const float* conv2_b  = (const float*)d_in[11];
    const float* bn2_g    = (const float*)d_in[12];
    const float* bn2_b    = (const float*)d_in[13];
    const float* bn2_m    = (const float*)d_in[14];
    const float* bn2_v    = (const float*)d_in[15];
    const float* proj_w   = (const float*)d_in[16];
    const float* proj_b   = (const float*)d_in[17];
    const float* mlp1_w   = (const float*)d_in[18];
    const float* mlp1_b   = (const float*)d_in[19];
    const float* mlp2_w   = (const float*)d_in[20];
    const float* mlp2_b   = (const float*)d_in[21];
    const float* ln_g     = (const float*)d_in[22];
    const float* ln_b     = (const float*)d_in[23];
    float* out = (float*)d_out;
    float* ws  = (float*)d_ws;

    unsigned short* ws_e   = (unsigned short*)(ws + OFF_E);
    unsigned short* ws_xb  = (unsigned short*)(ws + OFF_XB);
    unsigned short* ws_w2p = (unsigned short*)(ws + OFF_W2P);
    float* ws_part = ws + OFF_PART;
    unsigned short* ws_zbf = (unsigned short*)(ws + OFF_Z);
    float* ws_z1   = ws + OFF_Z1;
    unsigned short* ws_gbf = (unsigned short*)(ws + OFF_G);
    float* ws_y    = ws + OFF_Y;
    unsigned short* ws_w1b = (unsigned short*)(ws + OFF_W1B);
    unsigned short* ws_w2b = (unsigned short*)(ws + OFF_W2B);
    unsigned short* ws_wcb = (unsigned short*)(ws + OFF_WCB);
    float* ws_b1f  = ws + OFF_B1F;
    float* ws_sc2  = ws + OFF_SC2;
    float* ws_sh2  = ws + OFF_SH2;

    hipLaunchKernelGGL(k_pack, dim3((NPK_X + 255) / 256), dim3(256), 0, stream,
                       x, conv1_w, conv1_b, bn1_g, bn1_b, bn1_m, bn1_v,
                       conv2_b, bn2_g, bn2_b, bn2_m, bn2_v,
                       ws_xb, ws_wcb, ws_b1f, ws_sc2, ws_sh2);

    hipLaunchKernelGGL(k_einsum, dim3(NEIN), dim3(256), 0, stream,
                       ws_xb, W_sub, sid, b_sub, mlp1_w, mlp2_w, conv2_w,
                       ws_e, ws_w1b, ws_w2b, ws_w2p);

    hipLaunchKernelGGL(k_fc, dim3(KSPLIT, BB), dim3(384), 0, stream,
                       ws_e, ws_wcb, ws_b1f, ws_w2p, ws_part);

    hipLaunchKernelGGL(k_redproj, dim3(8, BB), dim3(256), 0, stream,
                       ws_part, ws_sc2, ws_sh2, proj_w, proj_b, ws_zbf);

    hipLaunchKernelGGL(k_mlp1, dim3(128), dim3(256), 0, stream,
                       ws_zbf, ws_w1b, mlp1_b, ws_z1, ws_gbf);

    hipLaunchKernelGGL(k_mlp2, dim3(128), dim3(256), 0, stream,
                       ws_gbf, ws_z1, ws_w2b, mlp2_b, ws_y);

    hipLaunchKernelGGL(k_ln, dim3(BB), dim3(256), 0, stream,
                       ws_y, ln_g, ln_b, out);
}